// Round 1
// baseline (1185.017 us; speedup 1.0000x reference)
//
#include <hip/hip_runtime.h>

#define BB 8
#define CC 512
#define SS 1024   // H*W
#define EMB 512
#define HEADS 8
#define DH 64
#define GROUPS 32
#define CPG 16    // CC/GROUPS
#define EPS 1e-5f

// ---------------------------------------------------------------------------
// Kernel 1: QKV projections.  A = x viewed as [B*S, C] (transpose of x[B,C,S]),
// B = W [C, EMB].  Output layout [B, HEADS, S, DH].  gridDim.z in {0,1,2}
// selects Q / K / V.
// ---------------------------------------------------------------------------
__global__ __launch_bounds__(256) void qkv_gemm(
    const float* __restrict__ x,
    const float* __restrict__ Wq, const float* __restrict__ bq,
    const float* __restrict__ Wk, const float* __restrict__ bk,
    const float* __restrict__ Wv, const float* __restrict__ bv,
    float* __restrict__ Q, float* __restrict__ K, float* __restrict__ V)
{
    const float* Wm; const float* bias; float* out;
    if (blockIdx.z == 0)      { Wm = Wq; bias = bq; out = Q; }
    else if (blockIdx.z == 1) { Wm = Wk; bias = bk; out = K; }
    else                      { Wm = Wv; bias = bv; out = V; }

    __shared__ float As[16][64];
    __shared__ float Bs[16][64];

    const int tm0 = blockIdx.x * 64;        // row tile base in [0, B*S)
    const int tn0 = blockIdx.y * 64;        // col tile base in [0, EMB)
    const int b   = tm0 / SS;
    const int s0  = tm0 % SS;               // tile never crosses a batch (64 | 1024)
    const int tx = threadIdx.x, ty = threadIdx.y;
    const int t  = ty * 16 + tx;

    float acc[4][4] = {};

    for (int k0 = 0; k0 < CC; k0 += 16) {
        // A tile: As[kk][m] = x[b, k0+kk, s0+m]  (m fast -> contiguous in s)
        #pragma unroll
        for (int l = 0; l < 4; ++l) {
            int i = t + l * 256;
            int m = i & 63, kk = i >> 6;
            As[kk][m] = x[(size_t)b * CC * SS + (size_t)(k0 + kk) * SS + s0 + m];
        }
        // B tile: Bs[kk][n] = W[k0+kk, tn0+n]
        #pragma unroll
        for (int l = 0; l < 4; ++l) {
            int i = t + l * 256;
            int n = i & 63, kk = i >> 6;
            Bs[kk][n] = Wm[(size_t)(k0 + kk) * EMB + tn0 + n];
        }
        __syncthreads();
        #pragma unroll
        for (int kk = 0; kk < 16; ++kk) {
            float a[4], bvv[4];
            #pragma unroll
            for (int i = 0; i < 4; ++i) a[i] = As[kk][ty + 16 * i];
            #pragma unroll
            for (int j = 0; j < 4; ++j) bvv[j] = Bs[kk][tx + 16 * j];
            #pragma unroll
            for (int i = 0; i < 4; ++i)
                #pragma unroll
                for (int j = 0; j < 4; ++j)
                    acc[i][j] += a[i] * bvv[j];
        }
        __syncthreads();
    }

    // write: row s = s0 + ty + 16i, col = tn0 + tx + 16j -> [B,H,S,DH]
    #pragma unroll
    for (int i = 0; i < 4; ++i) {
        int srow = s0 + ty + 16 * i;
        #pragma unroll
        for (int j = 0; j < 4; ++j) {
            int col = tn0 + tx + 16 * j;
            int h = col >> 6, d = col & 63;
            out[(((size_t)b * HEADS + h) * SS + srow) * DH + d] = acc[i][j] + bias[col];
        }
    }
}

// ---------------------------------------------------------------------------
// Kernel 2: flash-style attention.  One block = 64 q-rows of one (b, h).
// 256 threads: thread t -> row r = t>>2, col-group g = t&3 (16 d-cols each).
// Online softmax with K/V tiles of 32 rows.  Output [B, S, EMB].
// ---------------------------------------------------------------------------
__global__ __launch_bounds__(256) void attn_kernel(
    const float* __restrict__ Q, const float* __restrict__ K,
    const float* __restrict__ V, float* __restrict__ Aout)
{
    __shared__ float Qs[64][65];
    __shared__ float Ks[32][65];
    __shared__ float Vs[32][65];
    __shared__ float Ps[64][33];

    const int q0 = blockIdx.x * 64;
    const int h  = blockIdx.y;
    const int b  = blockIdx.z;
    const size_t base = ((size_t)b * HEADS + h) * SS * DH;

    const int t = threadIdx.x;
    const int r = t >> 2;
    const int g = t & 3;

    #pragma unroll
    for (int l = 0; l < 16; ++l) {
        int i = t + l * 256;
        int d = i & 63, q = i >> 6;
        Qs[q][d] = Q[base + (size_t)(q0 + q) * DH + d];
    }

    float m = -1e30f, lsum = 0.f;
    float O[16] = {};
    const float scale = 0.125f;  // DH^-0.5

    for (int k0 = 0; k0 < SS; k0 += 32) {
        #pragma unroll
        for (int l = 0; l < 8; ++l) {
            int i = t + l * 256;
            int d = i & 63, kk = i >> 6;
            Ks[kk][d] = K[base + (size_t)(k0 + kk) * DH + d];
            Vs[kk][d] = V[base + (size_t)(k0 + kk) * DH + d];
        }
        __syncthreads();

        float sc[8];
        float lm = -1e30f;
        #pragma unroll
        for (int i = 0; i < 8; ++i) {
            int kk = g * 8 + i;
            float dot = 0.f;
            #pragma unroll
            for (int dd = 0; dd < 64; ++dd) dot += Qs[r][dd] * Ks[kk][dd];
            sc[i] = dot * scale;
            lm = fmaxf(lm, sc[i]);
        }
        lm = fmaxf(lm, __shfl_xor(lm, 1));
        lm = fmaxf(lm, __shfl_xor(lm, 2));
        const float newm = fmaxf(m, lm);
        const float alpha = __expf(m - newm);
        float ls = 0.f;
        #pragma unroll
        for (int i = 0; i < 8; ++i) {
            sc[i] = __expf(sc[i] - newm);
            ls += sc[i];
            Ps[r][g * 8 + i] = sc[i];
        }
        ls += __shfl_xor(ls, 1);
        ls += __shfl_xor(ls, 2);
        lsum = lsum * alpha + ls;
        m = newm;
        #pragma unroll
        for (int j = 0; j < 16; ++j) O[j] *= alpha;

        __syncthreads();   // Ps visible; scores phase done before V consumption

        #pragma unroll
        for (int kk = 0; kk < 32; ++kk) {
            float p = Ps[r][kk];
            #pragma unroll
            for (int j = 0; j < 16; ++j)
                O[j] += p * Vs[kk][g * 16 + j];
        }
        __syncthreads();   // protect Ks/Vs/Ps for next tile
    }

    const float inv = 1.f / lsum;
    const int q = q0 + r;
    #pragma unroll
    for (int j = 0; j < 16; ++j) {
        int d = g * 16 + j;
        Aout[((size_t)b * SS + q) * EMB + h * DH + d] = O[j] * inv;
    }
}

// ---------------------------------------------------------------------------
// Kernel 3: output projection + bias + residual.
// A = attn out [B*S, EMB] row-major, B = Wo [EMB, EMB].
// Y[b, s, c] = (A @ Wo)[row, c] + bo[c] + x[b, c, s]   (stored [B, S, C])
// ---------------------------------------------------------------------------
__global__ __launch_bounds__(256) void proj_gemm(
    const float* __restrict__ A, const float* __restrict__ Wo,
    const float* __restrict__ bo, const float* __restrict__ x,
    float* __restrict__ Y)
{
    __shared__ float As[16][65];
    __shared__ float Bs[16][64];

    const int tm0 = blockIdx.x * 64;
    const int tn0 = blockIdx.y * 64;
    const int b   = tm0 / SS;
    const int s0  = tm0 % SS;
    const int tx = threadIdx.x, ty = threadIdx.y;
    const int t  = ty * 16 + tx;

    float acc[4][4] = {};

    for (int k0 = 0; k0 < EMB; k0 += 16) {
        // A row-major: consecutive threads load consecutive k
        #pragma unroll
        for (int l = 0; l < 4; ++l) {
            int i = t + l * 256;
            int kk = i & 15, mm = i >> 4;
            As[kk][mm] = A[(size_t)(tm0 + mm) * EMB + k0 + kk];
        }
        #pragma unroll
        for (int l = 0; l < 4; ++l) {
            int i = t + l * 256;
            int n = i & 63, kk = i >> 6;
            Bs[kk][n] = Wo[(size_t)(k0 + kk) * EMB + tn0 + n];
        }
        __syncthreads();
        #pragma unroll
        for (int kk = 0; kk < 16; ++kk) {
            float a[4], bvv[4];
            #pragma unroll
            for (int i = 0; i < 4; ++i) a[i] = As[kk][ty + 16 * i];
            #pragma unroll
            for (int j = 0; j < 4; ++j) bvv[j] = Bs[kk][tx + 16 * j];
            #pragma unroll
            for (int i = 0; i < 4; ++i)
                #pragma unroll
                for (int j = 0; j < 4; ++j)
                    acc[i][j] += a[i] * bvv[j];
        }
        __syncthreads();
    }

    #pragma unroll
    for (int i = 0; i < 4; ++i) {
        int srow = s0 + ty + 16 * i;
        #pragma unroll
        for (int j = 0; j < 4; ++j) {
            int col = tn0 + tx + 16 * j;
            float v = acc[i][j] + bo[col]
                    + x[(size_t)b * CC * SS + (size_t)col * SS + srow];
            Y[((size_t)b * SS + srow) * CC + col] = v;
        }
    }
}

// ---------------------------------------------------------------------------
// Kernel 4: GroupNorm.  One block per (group, batch).  Y in [B, S, C].
// Output [B, C, S] via LDS-staged transpose (coalesced writes).
// ---------------------------------------------------------------------------
__global__ __launch_bounds__(256) void gnorm_kernel(
    const float* __restrict__ Y, const float* __restrict__ gw,
    const float* __restrict__ gb, float* __restrict__ out)
{
    __shared__ float red[8];
    __shared__ float stats[2];
    __shared__ float tileb[16][257];

    const int grp = blockIdx.x;       // 0..31
    const int b   = blockIdx.y;       // 0..7
    const int c0  = grp * CPG;
    const int t   = threadIdx.x;
    const int cl  = t & 15;           // channel lane
    const int sl  = t >> 4;           // s lane (0..15)

    // ---- phase 1: mean / var over 16 channels x 1024 spatial ----
    float sum = 0.f, sq = 0.f;
    for (int k = 0; k < 64; ++k) {
        int s = sl + k * 16;
        float v = Y[((size_t)b * SS + s) * CC + c0 + cl];
        sum += v; sq += v * v;
    }
    #pragma unroll
    for (int off = 32; off; off >>= 1) {
        sum += __shfl_down(sum, off);
        sq  += __shfl_down(sq, off);
    }
    const int wid = t >> 6;
    if ((t & 63) == 0) { red[wid] = sum; red[4 + wid] = sq; }
    __syncthreads();
    if (t == 0) {
        float s1 = red[0] + red[1] + red[2] + red[3];
        float s2 = red[4] + red[5] + red[6] + red[7];
        float mean = s1 / (float)(CPG * SS);
        float var  = s2 / (float)(CPG * SS) - mean * mean;
        stats[0] = mean;
        stats[1] = rsqrtf(var + EPS);
    }
    __syncthreads();
    const float mean = stats[0], rs = stats[1];

    // ---- phase 2: normalize + affine + transpose-write [B,C,S] ----
    const int c2 = t >> 4;            // channel for write phase
    const int sb = t & 15;            // s lane for write phase
    const float wgt = gw[c0 + c2], bet = gb[c0 + c2];
    for (int sBase = 0; sBase < SS; sBase += 256) {
        #pragma unroll
        for (int k = 0; k < 16; ++k) {
            int ssp = sl + k * 16;
            tileb[cl][ssp] = Y[((size_t)b * SS + sBase + ssp) * CC + c0 + cl];
        }
        __syncthreads();
        #pragma unroll
        for (int k = 0; k < 16; ++k) {
            float v = tileb[c2][sb + k * 16];
            out[(size_t)b * CC * SS + (size_t)(c0 + c2) * SS + sBase + sb + k * 16]
                = (v - mean) * rs * wgt + bet;
        }
        __syncthreads();
    }
}

// ---------------------------------------------------------------------------
extern "C" void kernel_launch(void* const* d_in, const int* in_sizes, int n_in,
                              void* d_out, int out_size, void* d_ws, size_t ws_size,
                              hipStream_t stream) {
    const float* x   = (const float*)d_in[0];
    const float* Wq  = (const float*)d_in[1];
    const float* bq  = (const float*)d_in[2];
    const float* Wk  = (const float*)d_in[3];
    const float* bk  = (const float*)d_in[4];
    const float* Wv  = (const float*)d_in[5];
    const float* bv  = (const float*)d_in[6];
    const float* Wo  = (const float*)d_in[7];
    const float* bo  = (const float*)d_in[8];
    const float* gnw = (const float*)d_in[9];
    const float* gnb = (const float*)d_in[10];
    float* out = (float*)d_out;
    float* ws  = (float*)d_ws;

    const size_t N = (size_t)BB * HEADS * SS * DH;   // 4,194,304 floats
    float* Q  = ws;
    float* K  = ws + N;
    float* V  = ws + 2 * N;
    float* AO = ws + 3 * N;     // [B, S, EMB]
    float* Y  = ws;             // reuse Q region (dead after attention)

    qkv_gemm<<<dim3(128, 8, 3), dim3(16, 16), 0, stream>>>(
        x, Wq, bq, Wk, bk, Wv, bv, Q, K, V);
    attn_kernel<<<dim3(16, 8, 8), dim3(256), 0, stream>>>(Q, K, V, AO);
    proj_gemm<<<dim3(128, 8), dim3(16, 16), 0, stream>>>(AO, Wo, bo, x, Y);
    gnorm_kernel<<<dim3(32, 8), dim3(256), 0, stream>>>(Y, gnw, gnb, out);
}

// Round 2
// 384.945 us; speedup vs baseline: 3.0784x; 3.0784x over previous
//
#include <hip/hip_runtime.h>

#define BB 8
#define CC 512
#define SS 1024   // H*W
#define EMB 512
#define HEADS 8
#define DH 64
#define GROUPS 32
#define CPG 16    // CC/GROUPS
#define EPS 1e-5f

typedef __bf16 bf16x8 __attribute__((ext_vector_type(8)));
typedef float f32x4 __attribute__((ext_vector_type(4)));
typedef unsigned short ushort8 __attribute__((ext_vector_type(8)));

__device__ inline unsigned short f2bf(float f) {
    union { float f; unsigned u; } c; c.f = f;
    unsigned u = c.u + 0x7FFF + ((c.u >> 16) & 1);   // RNE
    return (unsigned short)(u >> 16);
}

#define MFMA16(a, b, c) __builtin_amdgcn_mfma_f32_16x16x32_bf16((a), (b), (c), 0, 0, 0)

// ---------------------------------------------------------------------------
// Kernel 1: QKV projections (fp32 SGEMM, unchanged this round).
// ---------------------------------------------------------------------------
__global__ __launch_bounds__(256) void qkv_gemm(
    const float* __restrict__ x,
    const float* __restrict__ Wq, const float* __restrict__ bq,
    const float* __restrict__ Wk, const float* __restrict__ bk,
    const float* __restrict__ Wv, const float* __restrict__ bv,
    float* __restrict__ Q, float* __restrict__ K, float* __restrict__ V)
{
    const float* Wm; const float* bias; float* out;
    if (blockIdx.z == 0)      { Wm = Wq; bias = bq; out = Q; }
    else if (blockIdx.z == 1) { Wm = Wk; bias = bk; out = K; }
    else                      { Wm = Wv; bias = bv; out = V; }

    __shared__ float As[16][64];
    __shared__ float Bs[16][64];

    const int tm0 = blockIdx.x * 64;
    const int tn0 = blockIdx.y * 64;
    const int b   = tm0 / SS;
    const int s0  = tm0 % SS;
    const int tx = threadIdx.x, ty = threadIdx.y;
    const int t  = ty * 16 + tx;

    float acc[4][4] = {};

    for (int k0 = 0; k0 < CC; k0 += 16) {
        #pragma unroll
        for (int l = 0; l < 4; ++l) {
            int i = t + l * 256;
            int m = i & 63, kk = i >> 6;
            As[kk][m] = x[(size_t)b * CC * SS + (size_t)(k0 + kk) * SS + s0 + m];
        }
        #pragma unroll
        for (int l = 0; l < 4; ++l) {
            int i = t + l * 256;
            int n = i & 63, kk = i >> 6;
            Bs[kk][n] = Wm[(size_t)(k0 + kk) * EMB + tn0 + n];
        }
        __syncthreads();
        #pragma unroll
        for (int kk = 0; kk < 16; ++kk) {
            float a[4], bvv[4];
            #pragma unroll
            for (int i = 0; i < 4; ++i) a[i] = As[kk][ty + 16 * i];
            #pragma unroll
            for (int j = 0; j < 4; ++j) bvv[j] = Bs[kk][tx + 16 * j];
            #pragma unroll
            for (int i = 0; i < 4; ++i)
                #pragma unroll
                for (int j = 0; j < 4; ++j)
                    acc[i][j] += a[i] * bvv[j];
        }
        __syncthreads();
    }

    #pragma unroll
    for (int i = 0; i < 4; ++i) {
        int srow = s0 + ty + 16 * i;
        #pragma unroll
        for (int j = 0; j < 4; ++j) {
            int col = tn0 + tx + 16 * j;
            int h = col >> 6, d = col & 63;
            out[(((size_t)b * HEADS + h) * SS + srow) * DH + d] = acc[i][j] + bias[col];
        }
    }
}

// ---------------------------------------------------------------------------
// Kernel 2: MFMA flash attention.  256 threads = 4 waves; wave w owns 16
// q-rows.  K-tile = 32 rows.  Swapped QK^T (mfma(K,Q) -> S^T[kk][q]) so the
// softmax row-reduce is a 4-lane shfl group.  PV as mfma(V^T, P^T).
// LDS: Ks [32][128B] bf16 swizzled; Vt [64][128B] bf16 (transposed,
// swizzled); Ps per-wave [16][128B] bf16 swizzled.
// ---------------------------------------------------------------------------
__global__ __launch_bounds__(256) void attn_mfma(
    const float* __restrict__ Q, const float* __restrict__ K,
    const float* __restrict__ V, float* __restrict__ Aout)
{
    __shared__ __align__(16) char lds[20480];
    char* Ks = lds;                      // 4 KB
    char* Vt = lds + 4096;               // 8 KB
    // Ps: per-wave 2 KB at 12288 + w*2048

    const int q0 = blockIdx.x * 64;
    const int h  = blockIdx.y;
    const int b  = blockIdx.z;
    const size_t base = ((size_t)b * HEADS + h) * SS * DH;

    const int t  = threadIdx.x;
    const int w  = t >> 6;
    const int l  = t & 63;
    const int g  = l >> 4;               // 0..3
    const int qi = l & 15;               // 0..15
    char* Ps = lds + 12288 + w * 2048;

    // Q fragments, resident in registers: Q[q0+w*16+qi][c*32 + g*8 + j]
    bf16x8 qf[2];
    {
        const float* qrow = Q + base + (size_t)(q0 + w * 16 + qi) * DH;
        #pragma unroll
        for (int c = 0; c < 2; ++c) {
            float4 a  = *(const float4*)(qrow + c * 32 + g * 8);
            float4 bb = *(const float4*)(qrow + c * 32 + g * 8 + 4);
            union { ushort8 u; bf16x8 v; } cv;
            cv.u[0]=f2bf(a.x);  cv.u[1]=f2bf(a.y);  cv.u[2]=f2bf(a.z);  cv.u[3]=f2bf(a.w);
            cv.u[4]=f2bf(bb.x); cv.u[5]=f2bf(bb.y); cv.u[6]=f2bf(bb.z); cv.u[7]=f2bf(bb.w);
            qf[c] = cv.v;
        }
    }

    const int kk_s = t >> 3;             // staging row 0..31
    const int seg  = t & 7;              // 8-float segment
    const int kdst = kk_s * 128 + ((seg * 16) ^ ((kk_s & 7) << 4));

    f32x4 O[4] = {};                     // O^T[d=dt*16+4g+r][q=qi]
    float m = -1e30f, lsum = 0.f;
    const float scale = 0.125f;          // DH^-0.5

    for (int k0 = 0; k0 < SS; k0 += 32) {
        // ---- stage K (swizzled row-major bf16) ----
        {
            const float* src = K + base + (size_t)(k0 + kk_s) * DH + seg * 8;
            float4 a  = *(const float4*)src;
            float4 bb = *(const float4*)(src + 4);
            ushort8 u;
            u[0]=f2bf(a.x);  u[1]=f2bf(a.y);  u[2]=f2bf(a.z);  u[3]=f2bf(a.w);
            u[4]=f2bf(bb.x); u[5]=f2bf(bb.y); u[6]=f2bf(bb.z); u[7]=f2bf(bb.w);
            *(ushort8*)(Ks + kdst) = u;
        }
        // ---- stage V transposed: Vt[d][kk], swizzled ----
        {
            const float* src = V + base + (size_t)(k0 + kk_s) * DH + seg * 8;
            float4 a  = *(const float4*)src;
            float4 bb = *(const float4*)(src + 4);
            float f[8] = {a.x, a.y, a.z, a.w, bb.x, bb.y, bb.z, bb.w};
            #pragma unroll
            for (int j = 0; j < 8; ++j) {
                int d = seg * 8 + j;                 // d&7 == j
                *(unsigned short*)(Vt + d * 128 + ((kk_s * 2) ^ (j << 4))) = f2bf(f[j]);
            }
        }
        __syncthreads();

        // ---- QK^T swapped: st[tt][r] = S^T[kk=16*tt+4g+r][q=qi] ----
        f32x4 st[2] = {};
        #pragma unroll
        for (int tt = 0; tt < 2; ++tt) {
            int row = tt * 16 + qi;
            #pragma unroll
            for (int c = 0; c < 2; ++c) {
                bf16x8 kf = *(const bf16x8*)(Ks + row * 128 +
                              ((c * 64 + g * 16) ^ ((row & 7) << 4)));
                st[tt] = MFMA16(kf, qf[c], st[tt]);
            }
        }

        // ---- online softmax (reduce across the 4-lane g-group) ----
        float sv[8];
        float lm = -1e30f;
        #pragma unroll
        for (int tt = 0; tt < 2; ++tt)
            #pragma unroll
            for (int r = 0; r < 4; ++r) {
                float s = st[tt][r] * scale;
                sv[tt * 4 + r] = s;
                lm = fmaxf(lm, s);
            }
        lm = fmaxf(lm, __shfl_xor(lm, 16));
        lm = fmaxf(lm, __shfl_xor(lm, 32));
        const float newm  = fmaxf(m, lm);
        const float alpha = __expf(m - newm);
        float ls = 0.f;
        unsigned short p16[8];
        #pragma unroll
        for (int i = 0; i < 8; ++i) {
            float p = __expf(sv[i] - newm);
            ls += p;
            p16[i] = f2bf(p);
        }
        ls += __shfl_xor(ls, 16);
        ls += __shfl_xor(ls, 32);
        lsum = lsum * alpha + ls;
        m = newm;
        #pragma unroll
        for (int dt = 0; dt < 4; ++dt)
            #pragma unroll
            for (int r = 0; r < 4; ++r) O[dt][r] *= alpha;

        // ---- P -> per-wave LDS (bf16 pairs), then PV ----
        #pragma unroll
        for (int tt = 0; tt < 2; ++tt)
            #pragma unroll
            for (int rp = 0; rp < 2; ++rp) {
                int kk = tt * 16 + g * 4 + rp * 2;
                unsigned val = (unsigned)p16[tt * 4 + rp * 2]
                             | ((unsigned)p16[tt * 4 + rp * 2 + 1] << 16);
                *(unsigned*)(Ps + qi * 128 + ((kk * 2) ^ ((qi & 7) << 4))) = val;
            }
        bf16x8 pf = *(const bf16x8*)(Ps + qi * 128 + ((g * 16) ^ ((qi & 7) << 4)));
        #pragma unroll
        for (int dt = 0; dt < 4; ++dt) {
            int d = dt * 16 + qi;
            bf16x8 vf = *(const bf16x8*)(Vt + d * 128 + ((g * 16) ^ ((d & 7) << 4)));
            O[dt] = MFMA16(vf, pf, O[dt]);
        }
        __syncthreads();
    }

    // ---- epilogue: O^T[d][q] / lsum -> Aout[b][s][h*64+d] ----
    const float inv = 1.f / lsum;
    float* orow = Aout + ((size_t)b * SS + q0 + w * 16 + qi) * EMB + h * DH;
    #pragma unroll
    for (int dt = 0; dt < 4; ++dt) {
        float4 o;
        o.x = O[dt][0] * inv; o.y = O[dt][1] * inv;
        o.z = O[dt][2] * inv; o.w = O[dt][3] * inv;
        *(float4*)(orow + dt * 16 + g * 4) = o;
    }
}

// ---------------------------------------------------------------------------
// Kernel 3: output projection + bias + residual (fp32, unchanged).
// ---------------------------------------------------------------------------
__global__ __launch_bounds__(256) void proj_gemm(
    const float* __restrict__ A, const float* __restrict__ Wo,
    const float* __restrict__ bo, const float* __restrict__ x,
    float* __restrict__ Y)
{
    __shared__ float As[16][65];
    __shared__ float Bs[16][64];

    const int tm0 = blockIdx.x * 64;
    const int tn0 = blockIdx.y * 64;
    const int b   = tm0 / SS;
    const int s0  = tm0 % SS;
    const int tx = threadIdx.x, ty = threadIdx.y;
    const int t  = ty * 16 + tx;

    float acc[4][4] = {};

    for (int k0 = 0; k0 < EMB; k0 += 16) {
        #pragma unroll
        for (int l = 0; l < 4; ++l) {
            int i = t + l * 256;
            int kk = i & 15, mm = i >> 4;
            As[kk][mm] = A[(size_t)(tm0 + mm) * EMB + k0 + kk];
        }
        #pragma unroll
        for (int l = 0; l < 4; ++l) {
            int i = t + l * 256;
            int n = i & 63, kk = i >> 6;
            Bs[kk][n] = Wo[(size_t)(k0 + kk) * EMB + tn0 + n];
        }
        __syncthreads();
        #pragma unroll
        for (int kk = 0; kk < 16; ++kk) {
            float a[4], bvv[4];
            #pragma unroll
            for (int i = 0; i < 4; ++i) a[i] = As[kk][ty + 16 * i];
            #pragma unroll
            for (int j = 0; j < 4; ++j) bvv[j] = Bs[kk][tx + 16 * j];
            #pragma unroll
            for (int i = 0; i < 4; ++i)
                #pragma unroll
                for (int j = 0; j < 4; ++j)
                    acc[i][j] += a[i] * bvv[j];
        }
        __syncthreads();
    }

    #pragma unroll
    for (int i = 0; i < 4; ++i) {
        int srow = s0 + ty + 16 * i;
        #pragma unroll
        for (int j = 0; j < 4; ++j) {
            int col = tn0 + tx + 16 * j;
            float v = acc[i][j] + bo[col]
                    + x[(size_t)b * CC * SS + (size_t)col * SS + srow];
            Y[((size_t)b * SS + srow) * CC + col] = v;
        }
    }
}

// ---------------------------------------------------------------------------
// Kernel 4: GroupNorm (unchanged).
// ---------------------------------------------------------------------------
__global__ __launch_bounds__(256) void gnorm_kernel(
    const float* __restrict__ Y, const float* __restrict__ gw,
    const float* __restrict__ gb, float* __restrict__ out)
{
    __shared__ float red[8];
    __shared__ float stats[2];
    __shared__ float tileb[16][257];

    const int grp = blockIdx.x;
    const int b   = blockIdx.y;
    const int c0  = grp * CPG;
    const int t   = threadIdx.x;
    const int cl  = t & 15;
    const int sl  = t >> 4;

    float sum = 0.f, sq = 0.f;
    for (int k = 0; k < 64; ++k) {
        int s = sl + k * 16;
        float v = Y[((size_t)b * SS + s) * CC + c0 + cl];
        sum += v; sq += v * v;
    }
    #pragma unroll
    for (int off = 32; off; off >>= 1) {
        sum += __shfl_down(sum, off);
        sq  += __shfl_down(sq, off);
    }
    const int wid = t >> 6;
    if ((t & 63) == 0) { red[wid] = sum; red[4 + wid] = sq; }
    __syncthreads();
    if (t == 0) {
        float s1 = red[0] + red[1] + red[2] + red[3];
        float s2 = red[4] + red[5] + red[6] + red[7];
        float mean = s1 / (float)(CPG * SS);
        float var  = s2 / (float)(CPG * SS) - mean * mean;
        stats[0] = mean;
        stats[1] = rsqrtf(var + EPS);
    }
    __syncthreads();
    const float mean = stats[0], rs = stats[1];

    const int c2 = t >> 4;
    const int sb = t & 15;
    const float wgt = gw[c0 + c2], bet = gb[c0 + c2];
    for (int sBase = 0; sBase < SS; sBase += 256) {
        #pragma unroll
        for (int k = 0; k < 16; ++k) {
            int ssp = sl + k * 16;
            tileb[cl][ssp] = Y[((size_t)b * SS + sBase + ssp) * CC + c0 + cl];
        }
        __syncthreads();
        #pragma unroll
        for (int k = 0; k < 16; ++k) {
            float v = tileb[c2][sb + k * 16];
            out[(size_t)b * CC * SS + (size_t)(c0 + c2) * SS + sBase + sb + k * 16]
                = (v - mean) * rs * wgt + bet;
        }
        __syncthreads();
    }
}

// ---------------------------------------------------------------------------
extern "C" void kernel_launch(void* const* d_in, const int* in_sizes, int n_in,
                              void* d_out, int out_size, void* d_ws, size_t ws_size,
                              hipStream_t stream) {
    const float* x   = (const float*)d_in[0];
    const float* Wq  = (const float*)d_in[1];
    const float* bq  = (const float*)d_in[2];
    const float* Wk  = (const float*)d_in[3];
    const float* bk  = (const float*)d_in[4];
    const float* Wv  = (const float*)d_in[5];
    const float* bv  = (const float*)d_in[6];
    const float* Wo  = (const float*)d_in[7];
    const float* bo  = (const float*)d_in[8];
    const float* gnw = (const float*)d_in[9];
    const float* gnb = (const float*)d_in[10];
    float* out = (float*)d_out;
    float* ws  = (float*)d_ws;

    const size_t N = (size_t)BB * HEADS * SS * DH;
    float* Q  = ws;
    float* K  = ws + N;
    float* V  = ws + 2 * N;
    float* AO = ws + 3 * N;
    float* Y  = ws;            // reuse Q region (dead after attention)

    qkv_gemm<<<dim3(128, 8, 3), dim3(16, 16), 0, stream>>>(
        x, Wq, bq, Wk, bk, Wv, bv, Q, K, V);
    attn_mfma<<<dim3(16, 8, 8), dim3(256), 0, stream>>>(Q, K, V, AO);
    proj_gemm<<<dim3(128, 8), dim3(16, 16), 0, stream>>>(AO, Wo, bo, x, Y);
    gnorm_kernel<<<dim3(32, 8), dim3(256), 0, stream>>>(Y, gnw, gnb, out);
}

// Round 3
// 123.868 us; speedup vs baseline: 9.5667x; 3.1077x over previous
//
#include <hip/hip_runtime.h>

#define BB 8
#define CC 512
#define SS 1024   // H*W
#define EMB 512
#define HEADS 8
#define DH 64
#define GROUPS 32
#define CPG 16
#define EPS 1e-5f

typedef __bf16 bf16x8 __attribute__((ext_vector_type(8)));
typedef float f32x4 __attribute__((ext_vector_type(4)));
typedef unsigned short u16x4 __attribute__((ext_vector_type(4)));
typedef unsigned short u16x8 __attribute__((ext_vector_type(8)));

__device__ inline unsigned short f2bf(float f) {
    union { float f; unsigned u; } c; c.f = f;
    unsigned u = c.u + 0x7FFF + ((c.u >> 16) & 1);   // RNE
    return (unsigned short)(u >> 16);
}

#define MFMA16(a, b, c) __builtin_amdgcn_mfma_f32_16x16x32_bf16((a), (b), (c), 0, 0, 0)
#define GLOAD_LDS16(g, s)                                                     \
    __builtin_amdgcn_global_load_lds(                                         \
        (const __attribute__((address_space(1))) void*)(g),                   \
        (__attribute__((address_space(3))) void*)(s), 16, 0, 0)

// ---------------------------------------------------------------------------
// Prep 1: x [B][C][S] fp32  ->  xT [B*S][C] bf16   (transpose + cast)
// ---------------------------------------------------------------------------
__global__ __launch_bounds__(256) void prep_x(
    const float* __restrict__ x, unsigned short* __restrict__ xT)
{
    __shared__ float tile[32][33];
    const int s0 = blockIdx.x * 32;
    const int c0 = blockIdx.y * 32;
    const int b  = blockIdx.z;
    const int t  = threadIdx.x;

    {
        int c = t >> 3, s4 = (t & 7) * 4;
        float4 v = *(const float4*)(x + ((size_t)b * CC + c0 + c) * SS + s0 + s4);
        tile[c][s4] = v.x; tile[c][s4 + 1] = v.y;
        tile[c][s4 + 2] = v.z; tile[c][s4 + 3] = v.w;
    }
    __syncthreads();
    {
        int sr = t >> 3, c4 = (t & 7) * 4;
        u16x4 o;
        #pragma unroll
        for (int i = 0; i < 4; ++i) o[i] = f2bf(tile[c4 + i][sr]);
        *(u16x4*)(xT + ((size_t)(b << 10) + s0 + sr) * CC + c0 + c4) = o;
    }
}

// ---------------------------------------------------------------------------
// Prep 2: W [K][N] fp32 -> Wt [N][K] bf16, for Wq,Wk,Wv,Wo (blockIdx.z).
// ---------------------------------------------------------------------------
__global__ __launch_bounds__(256) void prep_w(
    const float* __restrict__ Wq, const float* __restrict__ Wk,
    const float* __restrict__ Wv, const float* __restrict__ Wo,
    unsigned short* __restrict__ Wt)
{
    __shared__ float tile[32][33];
    const int z = blockIdx.z;
    const float* W = (z == 0) ? Wq : (z == 1) ? Wk : (z == 2) ? Wv : Wo;
    unsigned short* dst = Wt + (size_t)z * EMB * CC;
    const int k0 = blockIdx.x * 32;
    const int n0 = blockIdx.y * 32;
    const int t  = threadIdx.x;

    {
        int k = t >> 3, n4 = (t & 7) * 4;
        float4 v = *(const float4*)(W + (size_t)(k0 + k) * EMB + n0 + n4);
        tile[k][n4] = v.x; tile[k][n4 + 1] = v.y;
        tile[k][n4 + 2] = v.z; tile[k][n4 + 3] = v.w;
    }
    __syncthreads();
    {
        int n = t >> 3, k4 = (t & 7) * 4;
        u16x4 o;
        #pragma unroll
        for (int i = 0; i < 4; ++i) o[i] = f2bf(tile[k4 + i][n]);
        *(u16x4*)(dst + (size_t)(n0 + n) * CC + k0 + k4) = o;
    }
}

// ---------------------------------------------------------------------------
// MFMA GEMM core (shared by qkv_mm / proj_mm):
// C[m][n] = sum_k A[m][k] * B[k][n];  A [M][512] bf16 row-major (K-major),
// Bt [N][512] bf16 row-major (K-major).  128x128 tile, BK=32, 4 waves 2x2,
// double-buffered LDS via global_load_lds(16B), slot-XOR swizzle
// slot ^= (row>>1)&3 (pre-swizzled global source, swizzled ds_read_b128).
// ---------------------------------------------------------------------------
#define GEMM_CORE(Aptr, Bptr)                                                  \
    __shared__ __align__(16) char lds[32768];                                  \
    const int t = threadIdx.x, w = t >> 6, l = t & 63;                         \
    const int wr = w >> 1, wc = w & 1;                                         \
    const int rl = l & 15, kh = l >> 4;                                        \
    f32x4 acc[4][4] = {};                                                      \
    {                                                                          \
        const int srow = w * 32 + (l >> 2);                                    \
        const int sslot = (l & 3) ^ ((srow >> 1) & 3);                         \
        const char* Ag0 = (const char*)(Aptr) + (size_t)(m0 + srow) * 1024 + sslot * 16;      \
        const char* Ag1 = (const char*)(Aptr) + (size_t)(m0 + srow + 16) * 1024 + (((l & 3) ^ (((srow + 16) >> 1) & 3)) * 16); \
        const char* Bg0 = (const char*)(Bptr) + (size_t)(n0 + srow) * 1024 + sslot * 16;      \
        const char* Bg1 = (const char*)(Bptr) + (size_t)(n0 + srow + 16) * 1024 + (((l & 3) ^ (((srow + 16) >> 1) & 3)) * 16); \
        for (int kt = 0; kt < 16; ++kt) {                                      \
            if (kt == 0) {                                                     \
                GLOAD_LDS16(Ag0, lds + w * 2048);                              \
                GLOAD_LDS16(Ag1, lds + w * 2048 + 1024);                       \
                GLOAD_LDS16(Bg0, lds + 8192 + w * 2048);                       \
                GLOAD_LDS16(Bg1, lds + 8192 + w * 2048 + 1024);                \
                __syncthreads();                                               \
            }                                                                  \
            const int buf = kt & 1;                                            \
            if (kt < 15) {                                                     \
                const int kb = (kt + 1) * 64;                                  \
                char* Al = lds + (buf ^ 1) * 16384;                            \
                char* Bl = Al + 8192;                                          \
                GLOAD_LDS16(Ag0 + kb, Al + w * 2048);                          \
                GLOAD_LDS16(Ag1 + kb, Al + w * 2048 + 1024);                   \
                GLOAD_LDS16(Bg0 + kb, Bl + w * 2048);                          \
                GLOAD_LDS16(Bg1 + kb, Bl + w * 2048 + 1024);                   \
            }                                                                  \
            const char* Al = lds + buf * 16384;                                \
            const char* Bl = Al + 8192;                                        \
            bf16x8 af[4], bfr[4];                                              \
            _Pragma("unroll")                                                  \
            for (int i = 0; i < 4; ++i) {                                      \
                int row = wr * 64 + i * 16 + rl;                               \
                af[i] = *(const bf16x8*)(Al + row * 64 + ((kh ^ ((row >> 1) & 3)) << 4)); \
                int col = wc * 64 + i * 16 + rl;                               \
                bfr[i] = *(const bf16x8*)(Bl + col * 64 + ((kh ^ ((col >> 1) & 3)) << 4)); \
            }                                                                  \
            _Pragma("unroll")                                                  \
            for (int i = 0; i < 4; ++i)                                        \
                _Pragma("unroll")                                              \
                for (int j = 0; j < 4; ++j)                                    \
                    acc[i][j] = MFMA16(af[i], bfr[j], acc[i][j]);              \
            __syncthreads();                                                   \
        }                                                                      \
    }

// QKV: A = xT, B = Wt[z]; out = Q/K/V bf16 [B][H][S][DH], +bias.
__global__ __launch_bounds__(256) void qkv_mm(
    const unsigned short* __restrict__ xT, const unsigned short* __restrict__ Wt,
    const float* __restrict__ bq, const float* __restrict__ bk,
    const float* __restrict__ bv,
    unsigned short* __restrict__ Qb, unsigned short* __restrict__ Kb,
    unsigned short* __restrict__ Vb)
{
    const int z = blockIdx.z;
    const unsigned short* Bt = Wt + (size_t)z * EMB * CC;
    const float* bias = (z == 0) ? bq : (z == 1) ? bk : bv;
    unsigned short* outp = (z == 0) ? Qb : (z == 1) ? Kb : Vb;
    const int m0 = blockIdx.x * 128, n0 = blockIdx.y * 128;

    GEMM_CORE(xT, Bt)

    #pragma unroll
    for (int i = 0; i < 4; ++i) {
        #pragma unroll
        for (int j = 0; j < 4; ++j) {
            int n = n0 + wc * 64 + j * 16 + rl;
            int h = n >> 6, d = n & 63;
            float bi = bias[n];
            #pragma unroll
            for (int r = 0; r < 4; ++r) {
                int m = m0 + wr * 64 + i * 16 + kh * 4 + r;
                int b = m >> 10, s = m & 1023;
                outp[(((size_t)(b * HEADS + h)) * SS + s) * DH + d] =
                    f2bf(acc[i][j][r] + bi);
            }
        }
    }
}

// proj: A = AO bf16, B = Wot; out Y fp32 [B][C][S] = acc + bo + x residual.
__global__ __launch_bounds__(256) void proj_mm(
    const unsigned short* __restrict__ AO, const unsigned short* __restrict__ Wot,
    const float* __restrict__ bo, const float* __restrict__ x,
    float* __restrict__ Y)
{
    const int m0 = blockIdx.x * 128, n0 = blockIdx.y * 128;

    GEMM_CORE(AO, Wot)

    #pragma unroll
    for (int i = 0; i < 4; ++i) {
        #pragma unroll
        for (int j = 0; j < 4; ++j) {
            int n = n0 + wc * 64 + j * 16 + rl;          // channel c
            float bi = bo[n];
            int mb = m0 + wr * 64 + i * 16 + kh * 4;
            int b = mb >> 10, s = mb & 1023;
            const float4 xr = *(const float4*)(x + ((size_t)b * CC + n) * SS + s);
            float4 o;
            o.x = acc[i][j][0] + bi + xr.x;
            o.y = acc[i][j][1] + bi + xr.y;
            o.z = acc[i][j][2] + bi + xr.z;
            o.w = acc[i][j][3] + bi + xr.w;
            *(float4*)(Y + ((size_t)b * CC + n) * SS + s) = o;
        }
    }
}

// ---------------------------------------------------------------------------
// MFMA flash attention, bf16 Q/K/V in, bf16 AO out.
// ---------------------------------------------------------------------------
__global__ __launch_bounds__(256) void attn_mfma(
    const unsigned short* __restrict__ Q, const unsigned short* __restrict__ K,
    const unsigned short* __restrict__ V, unsigned short* __restrict__ Aout)
{
    __shared__ __align__(16) char lds[20480];
    char* Ks = lds;                      // 4 KB
    char* Vt = lds + 4096;               // 8 KB

    const int q0 = blockIdx.x * 64;
    const int h  = blockIdx.y;
    const int b  = blockIdx.z;
    const size_t base = ((size_t)b * HEADS + h) * SS * DH;

    const int t  = threadIdx.x;
    const int w  = t >> 6;
    const int l  = t & 63;
    const int g  = l >> 4;
    const int qi = l & 15;
    char* Ps = lds + 12288 + w * 2048;

    // Q fragments resident in registers
    bf16x8 qf[2];
    {
        const unsigned short* qrow = Q + base + (size_t)(q0 + w * 16 + qi) * DH;
        qf[0] = *(const bf16x8*)(qrow + g * 8);
        qf[1] = *(const bf16x8*)(qrow + 32 + g * 8);
    }

    // K staging via global_load_lds with pre-swizzled source
    const int krow = w * 8 + (l >> 3);           // 0..31
    const int kslot = (l & 7) ^ (krow & 7);      // source 16B segment
    const unsigned short* kg = K + base + (size_t)krow * DH + kslot * 8;

    // V staging (manual transpose scatter)
    const int kk_s = t >> 3;             // 0..31
    const int seg  = t & 7;

    f32x4 O[4] = {};
    float m = -1e30f, lsum = 0.f;
    const float scale = 0.125f;

    for (int k0 = 0; k0 < SS; k0 += 32) {
        GLOAD_LDS16(kg + (size_t)k0 * DH, Ks + w * 1024);
        {
            u16x8 u = *(const u16x8*)(V + base + (size_t)(k0 + kk_s) * DH + seg * 8);
            #pragma unroll
            for (int j = 0; j < 8; ++j)
                *(unsigned short*)(Vt + (seg * 8 + j) * 128 + ((kk_s * 2) ^ (j << 4))) = u[j];
        }
        __syncthreads();

        // QK^T swapped: st[tt] = S^T[kk = tt*16 + 4g+r][q = qi]
        f32x4 st[2] = {};
        #pragma unroll
        for (int tt = 0; tt < 2; ++tt) {
            int row = tt * 16 + qi;
            #pragma unroll
            for (int c = 0; c < 2; ++c) {
                bf16x8 kf = *(const bf16x8*)(Ks + row * 128 +
                              ((c * 64 + g * 16) ^ ((row & 7) << 4)));
                st[tt] = MFMA16(kf, qf[c], st[tt]);
            }
        }

        // online softmax across the 4-lane g-group
        float sv[8];
        float lm = -1e30f;
        #pragma unroll
        for (int tt = 0; tt < 2; ++tt)
            #pragma unroll
            for (int r = 0; r < 4; ++r) {
                float s = st[tt][r] * scale;
                sv[tt * 4 + r] = s;
                lm = fmaxf(lm, s);
            }
        lm = fmaxf(lm, __shfl_xor(lm, 16));
        lm = fmaxf(lm, __shfl_xor(lm, 32));
        const float newm  = fmaxf(m, lm);
        const float alpha = __expf(m - newm);
        float ls = 0.f;
        unsigned short p16[8];
        #pragma unroll
        for (int i = 0; i < 8; ++i) {
            float p = __expf(sv[i] - newm);
            ls += p;
            p16[i] = f2bf(p);
        }
        ls += __shfl_xor(ls, 16);
        ls += __shfl_xor(ls, 32);
        lsum = lsum * alpha + ls;
        m = newm;
        #pragma unroll
        for (int dt = 0; dt < 4; ++dt)
            #pragma unroll
            for (int r = 0; r < 4; ++r) O[dt][r] *= alpha;

        // P -> per-wave LDS, then PV
        #pragma unroll
        for (int tt = 0; tt < 2; ++tt)
            #pragma unroll
            for (int rp = 0; rp < 2; ++rp) {
                int kk = tt * 16 + g * 4 + rp * 2;
                unsigned val = (unsigned)p16[tt * 4 + rp * 2]
                             | ((unsigned)p16[tt * 4 + rp * 2 + 1] << 16);
                *(unsigned*)(Ps + qi * 128 + ((kk * 2) ^ ((qi & 7) << 4))) = val;
            }
        bf16x8 pf = *(const bf16x8*)(Ps + qi * 128 + ((g * 16) ^ ((qi & 7) << 4)));
        #pragma unroll
        for (int dt = 0; dt < 4; ++dt) {
            int d = dt * 16 + qi;
            bf16x8 vf = *(const bf16x8*)(Vt + d * 128 + ((g * 16) ^ ((d & 7) << 4)));
            O[dt] = MFMA16(vf, pf, O[dt]);
        }
        __syncthreads();
    }

    // epilogue: bf16 AO [B*S][EMB]
    const float inv = 1.f / lsum;
    unsigned short* orow = Aout + ((size_t)b * SS + q0 + w * 16 + qi) * EMB + h * DH;
    #pragma unroll
    for (int dt = 0; dt < 4; ++dt) {
        u16x4 o;
        #pragma unroll
        for (int r = 0; r < 4; ++r) o[r] = f2bf(O[dt][r] * inv);
        *(u16x4*)(orow + dt * 16 + g * 4) = o;
    }
}

// ---------------------------------------------------------------------------
// GroupNorm, pure streaming on [B][C][S].
// ---------------------------------------------------------------------------
__global__ __launch_bounds__(256) void gnorm2(
    const float* __restrict__ Y, const float* __restrict__ gw,
    const float* __restrict__ gb, float* __restrict__ out)
{
    __shared__ float red[8];
    __shared__ float stats[2];

    const int grp = blockIdx.x;
    const int b   = blockIdx.y;
    const int t   = threadIdx.x;
    const size_t base = ((size_t)b * CC + grp * CPG) * SS;   // 16384 floats

    float sum = 0.f, sq = 0.f;
    #pragma unroll
    for (int i = 0; i < 16; ++i) {
        float4 v = *(const float4*)(Y + base + (size_t)(t + i * 256) * 4);
        sum += v.x + v.y + v.z + v.w;
        sq  += v.x * v.x + v.y * v.y + v.z * v.z + v.w * v.w;
    }
    #pragma unroll
    for (int off = 32; off; off >>= 1) {
        sum += __shfl_down(sum, off);
        sq  += __shfl_down(sq, off);
    }
    const int wid = t >> 6;
    if ((t & 63) == 0) { red[wid] = sum; red[4 + wid] = sq; }
    __syncthreads();
    if (t == 0) {
        float s1 = red[0] + red[1] + red[2] + red[3];
        float s2 = red[4] + red[5] + red[6] + red[7];
        float mean = s1 / (float)(CPG * SS);
        float var  = s2 / (float)(CPG * SS) - mean * mean;
        stats[0] = mean;
        stats[1] = rsqrtf(var + EPS);
    }
    __syncthreads();
    const float mean = stats[0], rs = stats[1];

    #pragma unroll
    for (int i = 0; i < 16; ++i) {
        size_t idx = (size_t)(t + i * 256) * 4;
        int ch = grp * CPG + (int)(idx >> 10);
        float wgt = gw[ch], bet = gb[ch];
        float4 v = *(const float4*)(Y + base + idx);
        float4 o;
        o.x = (v.x - mean) * rs * wgt + bet;
        o.y = (v.y - mean) * rs * wgt + bet;
        o.z = (v.z - mean) * rs * wgt + bet;
        o.w = (v.w - mean) * rs * wgt + bet;
        *(float4*)(out + base + idx) = o;
    }
}

// ---------------------------------------------------------------------------
extern "C" void kernel_launch(void* const* d_in, const int* in_sizes, int n_in,
                              void* d_out, int out_size, void* d_ws, size_t ws_size,
                              hipStream_t stream) {
    const float* x   = (const float*)d_in[0];
    const float* Wq  = (const float*)d_in[1];
    const float* bq  = (const float*)d_in[2];
    const float* Wk  = (const float*)d_in[3];
    const float* bk  = (const float*)d_in[4];
    const float* Wv  = (const float*)d_in[5];
    const float* bv  = (const float*)d_in[6];
    const float* Wo  = (const float*)d_in[7];
    const float* bo  = (const float*)d_in[8];
    const float* gnw = (const float*)d_in[9];
    const float* gnb = (const float*)d_in[10];
    float* out = (float*)d_out;
    char* ws  = (char*)d_ws;

    // byte layout in ws
    unsigned short* xT  = (unsigned short*)(ws);                       //  8 MB
    unsigned short* Wt  = (unsigned short*)(ws + 8388608);             //  2 MB (4 matrices)
    unsigned short* Qb  = (unsigned short*)(ws + 10485760);            //  8 MB
    unsigned short* Kb  = (unsigned short*)(ws + 18874368);            //  8 MB
    unsigned short* Vb  = (unsigned short*)(ws + 27262976);            //  8 MB
    unsigned short* AO  = (unsigned short*)(ws + 35651584);            //  8 MB
    float*          Y   = (float*)(ws + 44040192);                     // 16 MB

    prep_x<<<dim3(32, 16, 8), 256, 0, stream>>>(x, xT);
    prep_w<<<dim3(16, 16, 4), 256, 0, stream>>>(Wq, Wk, Wv, Wo, Wt);
    qkv_mm<<<dim3(64, 4, 3), 256, 0, stream>>>(xT, Wt, bq, bk, bv, Qb, Kb, Vb);
    attn_mfma<<<dim3(16, 8, 8), 256, 0, stream>>>(Qb, Kb, Vb, AO);
    proj_mm<<<dim3(64, 4), 256, 0, stream>>>(AO, Wt + (size_t)3 * EMB * CC, bo, x, Y);
    gnorm2<<<dim3(32, 8), 256, 0, stream>>>(Y, gnw, gnb, out);
}

// Round 4
// 91.101 us; speedup vs baseline: 13.0077x; 1.3597x over previous
//
#include <hip/hip_runtime.h>

#define BB 8
#define CC 512
#define SS 1024   // H*W
#define EMB 512
#define HEADS 8
#define DH 64
#define GROUPS 32
#define CPG 16
#define EPS 1e-5f

typedef __bf16 bf16x8 __attribute__((ext_vector_type(8)));
typedef __bf16 bf16x4 __attribute__((ext_vector_type(4)));
typedef float f32x4 __attribute__((ext_vector_type(4)));
typedef unsigned short u16x4 __attribute__((ext_vector_type(4)));

__device__ inline unsigned short f2bf(float f) {
    union { float f; unsigned u; } c; c.f = f;
    unsigned u = c.u + 0x7FFF + ((c.u >> 16) & 1);   // RNE
    return (unsigned short)(u >> 16);
}

#if defined(__has_builtin)
#if __has_builtin(__builtin_amdgcn_exp2f)
#define EXP2F(x) __builtin_amdgcn_exp2f(x)
#endif
#endif
#ifndef EXP2F
#define EXP2F(x) __expf(0.69314718f * (x))
#endif

#define MFMA16(a, b, c) __builtin_amdgcn_mfma_f32_16x16x32_bf16((a), (b), (c), 0, 0, 0)
#define GLOAD_LDS16(g, s)                                                     \
    __builtin_amdgcn_global_load_lds(                                         \
        (const __attribute__((address_space(1))) void*)(g),                   \
        (__attribute__((address_space(3))) void*)(s), 16, 0, 0)

// ---------------------------------------------------------------------------
// Prep 1: x [B][C][S] fp32  ->  xT [B*S][C] bf16   (transpose + cast)
// ---------------------------------------------------------------------------
__global__ __launch_bounds__(256) void prep_x(
    const float* __restrict__ x, unsigned short* __restrict__ xT)
{
    __shared__ float tile[32][33];
    const int s0 = blockIdx.x * 32;
    const int c0 = blockIdx.y * 32;
    const int b  = blockIdx.z;
    const int t  = threadIdx.x;

    {
        int c = t >> 3, s4 = (t & 7) * 4;
        float4 v = *(const float4*)(x + ((size_t)b * CC + c0 + c) * SS + s0 + s4);
        tile[c][s4] = v.x; tile[c][s4 + 1] = v.y;
        tile[c][s4 + 2] = v.z; tile[c][s4 + 3] = v.w;
    }
    __syncthreads();
    {
        int sr = t >> 3, c4 = (t & 7) * 4;
        u16x4 o;
        #pragma unroll
        for (int i = 0; i < 4; ++i) o[i] = f2bf(tile[c4 + i][sr]);
        *(u16x4*)(xT + ((size_t)(b << 10) + s0 + sr) * CC + c0 + c4) = o;
    }
}

// ---------------------------------------------------------------------------
// Prep 2: W [K][N] fp32 -> Wt [N][K] bf16, for Wq,Wk,Wv,Wo (blockIdx.z).
// ---------------------------------------------------------------------------
__global__ __launch_bounds__(256) void prep_w(
    const float* __restrict__ Wq, const float* __restrict__ Wk,
    const float* __restrict__ Wv, const float* __restrict__ Wo,
    unsigned short* __restrict__ Wt)
{
    __shared__ float tile[32][33];
    const int z = blockIdx.z;
    const float* W = (z == 0) ? Wq : (z == 1) ? Wk : (z == 2) ? Wv : Wo;
    unsigned short* dst = Wt + (size_t)z * EMB * CC;
    const int k0 = blockIdx.x * 32;
    const int n0 = blockIdx.y * 32;
    const int t  = threadIdx.x;

    {
        int k = t >> 3, n4 = (t & 7) * 4;
        float4 v = *(const float4*)(W + (size_t)(k0 + k) * EMB + n0 + n4);
        tile[k][n4] = v.x; tile[k][n4 + 1] = v.y;
        tile[k][n4 + 2] = v.z; tile[k][n4 + 3] = v.w;
    }
    __syncthreads();
    {
        int n = t >> 3, k4 = (t & 7) * 4;
        u16x4 o;
        #pragma unroll
        for (int i = 0; i < 4; ++i) o[i] = f2bf(tile[k4 + i][n]);
        *(u16x4*)(dst + (size_t)(n0 + n) * CC + k0 + k4) = o;
    }
}

// ---------------------------------------------------------------------------
// MFMA GEMM core: 128x128 tile, BK=32, 4 waves 2x2, dbuf LDS via
// global_load_lds(16B), slot-XOR swizzle (pre-swizzled source).
// ---------------------------------------------------------------------------
#define GEMM_CORE(Aptr, Bptr)                                                  \
    __shared__ __align__(16) char lds[32768];                                  \
    const int t = threadIdx.x, w = t >> 6, l = t & 63;                         \
    const int wr = w >> 1, wc = w & 1;                                         \
    const int rl = l & 15, kh = l >> 4;                                        \
    f32x4 acc[4][4] = {};                                                      \
    {                                                                          \
        const int srow = w * 32 + (l >> 2);                                    \
        const int sslot = (l & 3) ^ ((srow >> 1) & 3);                         \
        const char* Ag0 = (const char*)(Aptr) + (size_t)(m0 + srow) * 1024 + sslot * 16;      \
        const char* Ag1 = (const char*)(Aptr) + (size_t)(m0 + srow + 16) * 1024 + (((l & 3) ^ (((srow + 16) >> 1) & 3)) * 16); \
        const char* Bg0 = (const char*)(Bptr) + (size_t)(n0 + srow) * 1024 + sslot * 16;      \
        const char* Bg1 = (const char*)(Bptr) + (size_t)(n0 + srow + 16) * 1024 + (((l & 3) ^ (((srow + 16) >> 1) & 3)) * 16); \
        for (int kt = 0; kt < 16; ++kt) {                                      \
            if (kt == 0) {                                                     \
                GLOAD_LDS16(Ag0, lds + w * 2048);                              \
                GLOAD_LDS16(Ag1, lds + w * 2048 + 1024);                       \
                GLOAD_LDS16(Bg0, lds + 8192 + w * 2048);                       \
                GLOAD_LDS16(Bg1, lds + 8192 + w * 2048 + 1024);                \
                __syncthreads();                                               \
            }                                                                  \
            const int buf = kt & 1;                                            \
            if (kt < 15) {                                                     \
                const int kb = (kt + 1) * 64;                                  \
                char* Al = lds + (buf ^ 1) * 16384;                            \
                char* Bl = Al + 8192;                                          \
                GLOAD_LDS16(Ag0 + kb, Al + w * 2048);                          \
                GLOAD_LDS16(Ag1 + kb, Al + w * 2048 + 1024);                   \
                GLOAD_LDS16(Bg0 + kb, Bl + w * 2048);                          \
                GLOAD_LDS16(Bg1 + kb, Bl + w * 2048 + 1024);                   \
            }                                                                  \
            const char* Al = lds + buf * 16384;                                \
            const char* Bl = Al + 8192;                                        \
            bf16x8 af[4], bfr[4];                                              \
            _Pragma("unroll")                                                  \
            for (int i = 0; i < 4; ++i) {                                      \
                int row = wr * 64 + i * 16 + rl;                               \
                af[i] = *(const bf16x8*)(Al + row * 64 + ((kh ^ ((row >> 1) & 3)) << 4)); \
                int col = wc * 64 + i * 16 + rl;                               \
                bfr[i] = *(const bf16x8*)(Bl + col * 64 + ((kh ^ ((col >> 1) & 3)) << 4)); \
            }                                                                  \
            _Pragma("unroll")                                                  \
            for (int i = 0; i < 4; ++i)                                        \
                _Pragma("unroll")                                              \
                for (int j = 0; j < 4; ++j)                                    \
                    acc[i][j] = MFMA16(af[i], bfr[j], acc[i][j]);              \
            __syncthreads();                                                   \
        }                                                                      \
    }

// QKV: A = xT, B = Wt[z].  Q/K bf16 [B][H][S][DH]; V bf16 TRANSPOSED
// [B][H][DH][S] so attention can stage V^T rows directly.
__global__ __launch_bounds__(256) void qkv_mm(
    const unsigned short* __restrict__ xT, const unsigned short* __restrict__ Wt,
    const float* __restrict__ bq, const float* __restrict__ bk,
    const float* __restrict__ bv,
    unsigned short* __restrict__ Qb, unsigned short* __restrict__ Kb,
    unsigned short* __restrict__ Vb)
{
    const int z = blockIdx.z;
    const unsigned short* Bt = Wt + (size_t)z * EMB * CC;
    const float* bias = (z == 0) ? bq : (z == 1) ? bk : bv;
    const int m0 = blockIdx.x * 128, n0 = blockIdx.y * 128;

    GEMM_CORE(xT, Bt)

    if (z == 2) {
        // V^T: [B][H][DH][S], 4 consecutive s -> vector store
        #pragma unroll
        for (int i = 0; i < 4; ++i) {
            #pragma unroll
            for (int j = 0; j < 4; ++j) {
                int n = n0 + wc * 64 + j * 16 + rl;
                int h = n >> 6, d = n & 63;
                float bi = bias[n];
                int mb = m0 + wr * 64 + i * 16 + kh * 4;
                int b = mb >> 10, s = mb & 1023;
                bf16x4 o;
                #pragma unroll
                for (int r = 0; r < 4; ++r) o[r] = (__bf16)(acc[i][j][r] + bi);
                *(bf16x4*)((__bf16*)Vb + (((size_t)(b * HEADS + h)) * DH + d) * SS + s) = o;
            }
        }
    } else {
        unsigned short* outp = (z == 0) ? Qb : Kb;
        #pragma unroll
        for (int i = 0; i < 4; ++i) {
            #pragma unroll
            for (int j = 0; j < 4; ++j) {
                int n = n0 + wc * 64 + j * 16 + rl;
                int h = n >> 6, d = n & 63;
                float bi = bias[n];
                #pragma unroll
                for (int r = 0; r < 4; ++r) {
                    int m = m0 + wr * 64 + i * 16 + kh * 4 + r;
                    int b = m >> 10, s = m & 1023;
                    outp[(((size_t)(b * HEADS + h)) * SS + s) * DH + d] =
                        f2bf(acc[i][j][r] + bi);
                }
            }
        }
    }
}

// proj: A = AO bf16, B = Wot; out Y fp32 [B][C][S] = acc + bo + x residual.
__global__ __launch_bounds__(256) void proj_mm(
    const unsigned short* __restrict__ AO, const unsigned short* __restrict__ Wot,
    const float* __restrict__ bo, const float* __restrict__ x,
    float* __restrict__ Y)
{
    const int m0 = blockIdx.x * 128, n0 = blockIdx.y * 128;

    GEMM_CORE(AO, Wot)

    #pragma unroll
    for (int i = 0; i < 4; ++i) {
        #pragma unroll
        for (int j = 0; j < 4; ++j) {
            int n = n0 + wc * 64 + j * 16 + rl;
            float bi = bo[n];
            int mb = m0 + wr * 64 + i * 16 + kh * 4;
            int b = mb >> 10, s = mb & 1023;
            const float4 xr = *(const float4*)(x + ((size_t)b * CC + n) * SS + s);
            float4 o;
            o.x = acc[i][j][0] + bi + xr.x;
            o.y = acc[i][j][1] + bi + xr.y;
            o.z = acc[i][j][2] + bi + xr.z;
            o.w = acc[i][j][3] + bi + xr.w;
            *(float4*)(Y + ((size_t)b * CC + n) * SS + s) = o;
        }
    }
}

// ---------------------------------------------------------------------------
// MFMA flash attention v2.  KVBLK=64, K and V^T both staged via
// global_load_lds (pre-swizzled source, slot^=row&7), 2-phase prefetch with
// one barrier per tile, defer-max softmax in exp2 domain, setprio around
// MFMA clusters, XCD-aware block remap.
// LDS: 2 x (K 8KB + Vt 8KB) + P 4x2KB = 40KB.
// ---------------------------------------------------------------------------
__global__ __launch_bounds__(256) void attn_mfma(
    const unsigned short* __restrict__ Q, const unsigned short* __restrict__ K,
    const unsigned short* __restrict__ V, unsigned short* __restrict__ Aout)
{
    __shared__ __align__(16) char lds[40960];

    // XCD-aware remap: all 16 q-blocks of one (b,h) on one XCD.
    const int wg  = blockIdx.x;
    const int xcd = wg & 7;
    const int idx = wg >> 3;
    const int pair = xcd * 8 + (idx >> 4);   // 0..63
    const int qb   = idx & 15;
    const int h = pair & 7;
    const int b = pair >> 3;
    const int q0 = qb * 64;

    const size_t kbase = ((size_t)b * HEADS + h) * SS * DH;   // Q,K layout
    const size_t vbase = ((size_t)b * HEADS + h) * DH * SS;   // V^T layout

    const int t  = threadIdx.x;
    const int w  = t >> 6;
    const int l  = t & 63;
    const int g  = l >> 4;
    const int qi = l & 15;
    char* Pl = lds + 32768 + w * 2048;

    // Q fragments resident in registers
    bf16x8 qf[2];
    {
        const unsigned short* qrow = Q + kbase + (size_t)(q0 + w * 16 + qi) * DH;
        qf[0] = *(const bf16x8*)(qrow + g * 8);
        qf[1] = *(const bf16x8*)(qrow + 32 + g * 8);
    }

    // staging addresses (pre-swizzled source, linear LDS dest)
    const int srow = t >> 3;             // 0..31
    const int seg  = t & 7;
    const unsigned short* kg0 = K + kbase + (size_t)srow * DH + ((seg ^ (srow & 7)) * 8);
    const unsigned short* vg0 = V + vbase + (size_t)srow * SS + ((seg ^ (srow & 7)) * 8);

#define ATTN_STAGE(bb, ktn)                                                    \
    GLOAD_LDS16(kg0 + (ktn) * 4096, lds + (bb) + t * 16);                      \
    GLOAD_LDS16(kg0 + (ktn) * 4096 + 2048, lds + (bb) + 4096 + t * 16);        \
    GLOAD_LDS16(vg0 + (ktn) * 64, lds + (bb) + 8192 + t * 16);                 \
    GLOAD_LDS16(vg0 + (ktn) * 64 + 32768, lds + (bb) + 12288 + t * 16);

    f32x4 O[4] = {};
    float m2 = -1e30f, lsum = 0.f;
    const float cscale = 0.125f * 1.44269504f;   // DH^-0.5 * log2(e)

    int bufb = 0;
    ATTN_STAGE(0, 0)
    __syncthreads();

    for (int kt = 0; kt < 16; ++kt) {
        if (kt < 15) { ATTN_STAGE(bufb ^ 16384, kt + 1) }

        const char* Kl = lds + bufb;
        const char* Vl = lds + bufb + 8192;

        // ---- QK^T swapped: st[tt][r] = S^T[kk=tt*16+g*4+r][q=qi] ----
        f32x4 st[4] = {};
        __builtin_amdgcn_s_setprio(1);
        #pragma unroll
        for (int tt = 0; tt < 4; ++tt) {
            int row = tt * 16 + qi;
            #pragma unroll
            for (int c = 0; c < 2; ++c) {
                bf16x8 kf = *(const bf16x8*)(Kl + row * 128 +
                              ((c * 64 + g * 16) ^ ((row & 7) << 4)));
                st[tt] = MFMA16(kf, qf[c], st[tt]);
            }
        }
        __builtin_amdgcn_s_setprio(0);

        // ---- softmax (exp2 domain, defer-max THR=8) ----
        float tv[16];
        float pmax = -1e30f;
        #pragma unroll
        for (int tt = 0; tt < 4; ++tt)
            #pragma unroll
            for (int r = 0; r < 4; ++r) {
                float v = st[tt][r] * cscale;
                tv[tt * 4 + r] = v;
                pmax = fmaxf(pmax, v);
            }
        if (!__all(pmax <= m2 + 8.0f)) {
            float gm = fmaxf(pmax, __shfl_xor(pmax, 16));
            gm = fmaxf(gm, __shfl_xor(gm, 32));
            float newm = fmaxf(m2, gm);
            float alpha = EXP2F(m2 - newm);
            #pragma unroll
            for (int dt = 0; dt < 4; ++dt)
                #pragma unroll
                for (int r = 0; r < 4; ++r) O[dt][r] *= alpha;
            lsum *= alpha;
            m2 = newm;
        }
        #pragma unroll
        for (int tt = 0; tt < 4; ++tt) {
            bf16x4 pk;
            #pragma unroll
            for (int r = 0; r < 4; ++r) {
                float p = EXP2F(tv[tt * 4 + r] - m2);
                lsum += p;
                pk[r] = (__bf16)p;
            }
            *(bf16x4*)(Pl + qi * 128 + ((tt * 32 + g * 8) ^ ((qi & 7) << 4))) = pk;
        }

        // ---- PV: O^T[d][q] += V^T[d][k] P^T[k][q] ----
        bf16x8 pf0 = *(const bf16x8*)(Pl + qi * 128 + ((g * 16) ^ ((qi & 7) << 4)));
        bf16x8 pf1 = *(const bf16x8*)(Pl + qi * 128 + ((64 + g * 16) ^ ((qi & 7) << 4)));
        __builtin_amdgcn_s_setprio(1);
        #pragma unroll
        for (int dt = 0; dt < 4; ++dt) {
            int d = dt * 16 + qi;
            bf16x8 vf0 = *(const bf16x8*)(Vl + d * 128 + ((g * 16) ^ ((d & 7) << 4)));
            O[dt] = MFMA16(vf0, pf0, O[dt]);
            bf16x8 vf1 = *(const bf16x8*)(Vl + d * 128 + ((64 + g * 16) ^ ((d & 7) << 4)));
            O[dt] = MFMA16(vf1, pf1, O[dt]);
        }
        __builtin_amdgcn_s_setprio(0);

        __syncthreads();
        bufb ^= 16384;
    }

    // ---- epilogue ----
    lsum += __shfl_xor(lsum, 16);
    lsum += __shfl_xor(lsum, 32);
    const float inv = __builtin_amdgcn_rcpf(lsum);
    unsigned short* orow = Aout + ((size_t)b * SS + q0 + w * 16 + qi) * EMB + h * DH;
    #pragma unroll
    for (int dt = 0; dt < 4; ++dt) {
        bf16x4 o;
        #pragma unroll
        for (int r = 0; r < 4; ++r) o[r] = (__bf16)(O[dt][r] * inv);
        *(bf16x4*)((__bf16*)orow + dt * 16 + g * 4) = o;
    }
#undef ATTN_STAGE
}

// ---------------------------------------------------------------------------
// GroupNorm, pure streaming on [B][C][S].
// ---------------------------------------------------------------------------
__global__ __launch_bounds__(256) void gnorm2(
    const float* __restrict__ Y, const float* __restrict__ gw,
    const float* __restrict__ gb, float* __restrict__ out)
{
    __shared__ float red[8];
    __shared__ float stats[2];

    const int grp = blockIdx.x;
    const int b   = blockIdx.y;
    const int t   = threadIdx.x;
    const size_t base = ((size_t)b * CC + grp * CPG) * SS;

    float sum = 0.f, sq = 0.f;
    #pragma unroll
    for (int i = 0; i < 16; ++i) {
        float4 v = *(const float4*)(Y + base + (size_t)(t + i * 256) * 4);
        sum += v.x + v.y + v.z + v.w;
        sq  += v.x * v.x + v.y * v.y + v.z * v.z + v.w * v.w;
    }
    #pragma unroll
    for (int off = 32; off; off >>= 1) {
        sum += __shfl_down(sum, off);
        sq  += __shfl_down(sq, off);
    }
    const int wid = t >> 6;
    if ((t & 63) == 0) { red[wid] = sum; red[4 + wid] = sq; }
    __syncthreads();
    if (t == 0) {
        float s1 = red[0] + red[1] + red[2] + red[3];
        float s2 = red[4] + red[5] + red[6] + red[7];
        float mean = s1 / (float)(CPG * SS);
        float var  = s2 / (float)(CPG * SS) - mean * mean;
        stats[0] = mean;
        stats[1] = rsqrtf(var + EPS);
    }
    __syncthreads();
    const float mean = stats[0], rs = stats[1];

    #pragma unroll
    for (int i = 0; i < 16; ++i) {
        size_t idx = (size_t)(t + i * 256) * 4;
        int ch = grp * CPG + (int)(idx >> 10);
        float wgt = gw[ch], bet = gb[ch];
        float4 v = *(const float4*)(Y + base + idx);
        float4 o;
        o.x = (v.x - mean) * rs * wgt + bet;
        o.y = (v.y - mean) * rs * wgt + bet;
        o.z = (v.z - mean) * rs * wgt + bet;
        o.w = (v.w - mean) * rs * wgt + bet;
        *(float4*)(out + base + idx) = o;
    }
}

// ---------------------------------------------------------------------------
extern "C" void kernel_launch(void* const* d_in, const int* in_sizes, int n_in,
                              void* d_out, int out_size, void* d_ws, size_t ws_size,
                              hipStream_t stream) {
    const float* x   = (const float*)d_in[0];
    const float* Wq  = (const float*)d_in[1];
    const float* bq  = (const float*)d_in[2];
    const float* Wk  = (const float*)d_in[3];
    const float* bk  = (const float*)d_in[4];
    const float* Wv  = (const float*)d_in[5];
    const float* bv  = (const float*)d_in[6];
    const float* Wo  = (const float*)d_in[7];
    const float* bo  = (const float*)d_in[8];
    const float* gnw = (const float*)d_in[9];
    const float* gnb = (const float*)d_in[10];
    float* out = (float*)d_out;
    char* ws  = (char*)d_ws;

    unsigned short* xT  = (unsigned short*)(ws);                       //  8 MB
    unsigned short* Wt  = (unsigned short*)(ws + 8388608);             //  2 MB
    unsigned short* Qb  = (unsigned short*)(ws + 10485760);            //  8 MB
    unsigned short* Kb  = (unsigned short*)(ws + 18874368);            //  8 MB
    unsigned short* Vb  = (unsigned short*)(ws + 27262976);            //  8 MB (V^T)
    unsigned short* AO  = (unsigned short*)(ws + 35651584);            //  8 MB
    float*          Y   = (float*)(ws + 44040192);                     // 16 MB

    prep_x<<<dim3(32, 16, 8), 256, 0, stream>>>(x, xT);
    prep_w<<<dim3(16, 16, 4), 256, 0, stream>>>(Wq, Wk, Wv, Wo, Wt);
    qkv_mm<<<dim3(64, 4, 3), 256, 0, stream>>>(xT, Wt, bq, bk, bv, Qb, Kb, Vb);
    attn_mfma<<<dim3(1024), 256, 0, stream>>>(Qb, Kb, Vb, AO);
    proj_mm<<<dim3(64, 4), 256, 0, stream>>>(AO, Wt + (size_t)3 * EMB * CC, bo, x, Y);
    gnorm2<<<dim3(32, 8), 256, 0, stream>>>(Y, gnw, gnb, out);
}

// Round 5
// 87.102 us; speedup vs baseline: 13.6050x; 1.0459x over previous
//
#include <hip/hip_runtime.h>

#define BB 8
#define CC 512
#define SS 1024   // H*W
#define EMB 512
#define HEADS 8
#define DH 64
#define GROUPS 32
#define CPG 16
#define EPS 1e-5f

typedef __bf16 bf16x8 __attribute__((ext_vector_type(8)));
typedef __bf16 bf16x4 __attribute__((ext_vector_type(4)));
typedef float f32x4 __attribute__((ext_vector_type(4)));
typedef unsigned short u16x4 __attribute__((ext_vector_type(4)));

__device__ inline unsigned short f2bf(float f) {
    union { float f; unsigned u; } c; c.f = f;
    unsigned u = c.u + 0x7FFF + ((c.u >> 16) & 1);   // RNE
    return (unsigned short)(u >> 16);
}

#if defined(__has_builtin)
#if __has_builtin(__builtin_amdgcn_exp2f)
#define EXP2F(x) __builtin_amdgcn_exp2f(x)
#endif
#endif
#ifndef EXP2F
#define EXP2F(x) __expf(0.69314718f * (x))
#endif

#define MFMA16(a, b, c) __builtin_amdgcn_mfma_f32_16x16x32_bf16((a), (b), (c), 0, 0, 0)
#define GLOAD_LDS16(g, s)                                                     \
    __builtin_amdgcn_global_load_lds(                                         \
        (const __attribute__((address_space(1))) void*)(g),                   \
        (__attribute__((address_space(3))) void*)(s), 16, 0, 0)

// ---------------------------------------------------------------------------
// Prep 1: x [B][C][S] fp32  ->  xT [B*S][C] bf16   (transpose + cast)
// ---------------------------------------------------------------------------
__global__ __launch_bounds__(256) void prep_x(
    const float* __restrict__ x, unsigned short* __restrict__ xT)
{
    __shared__ float tile[32][33];
    const int s0 = blockIdx.x * 32;
    const int c0 = blockIdx.y * 32;
    const int b  = blockIdx.z;
    const int t  = threadIdx.x;

    {
        int c = t >> 3, s4 = (t & 7) * 4;
        float4 v = *(const float4*)(x + ((size_t)b * CC + c0 + c) * SS + s0 + s4);
        tile[c][s4] = v.x; tile[c][s4 + 1] = v.y;
        tile[c][s4 + 2] = v.z; tile[c][s4 + 3] = v.w;
    }
    __syncthreads();
    {
        int sr = t >> 3, c4 = (t & 7) * 4;
        u16x4 o;
        #pragma unroll
        for (int i = 0; i < 4; ++i) o[i] = f2bf(tile[c4 + i][sr]);
        *(u16x4*)(xT + ((size_t)(b << 10) + s0 + sr) * CC + c0 + c4) = o;
    }
}

// ---------------------------------------------------------------------------
// Prep 2: W [K][N] fp32 -> Wt [N][K] bf16, for Wq,Wk,Wv,Wo (blockIdx.z).
// ---------------------------------------------------------------------------
__global__ __launch_bounds__(256) void prep_w(
    const float* __restrict__ Wq, const float* __restrict__ Wk,
    const float* __restrict__ Wv, const float* __restrict__ Wo,
    unsigned short* __restrict__ Wt)
{
    __shared__ float tile[32][33];
    const int z = blockIdx.z;
    const float* W = (z == 0) ? Wq : (z == 1) ? Wk : (z == 2) ? Wv : Wo;
    unsigned short* dst = Wt + (size_t)z * EMB * CC;
    const int k0 = blockIdx.x * 32;
    const int n0 = blockIdx.y * 32;
    const int t  = threadIdx.x;

    {
        int k = t >> 3, n4 = (t & 7) * 4;
        float4 v = *(const float4*)(W + (size_t)(k0 + k) * EMB + n0 + n4);
        tile[k][n4] = v.x; tile[k][n4 + 1] = v.y;
        tile[k][n4 + 2] = v.z; tile[k][n4 + 3] = v.w;
    }
    __syncthreads();
    {
        int n = t >> 3, k4 = (t & 7) * 4;
        u16x4 o;
        #pragma unroll
        for (int i = 0; i < 4; ++i) o[i] = f2bf(tile[k4 + i][n]);
        *(u16x4*)(dst + (size_t)(n0 + n) * CC + k0 + k4) = o;
    }
}

// ---------------------------------------------------------------------------
// MFMA GEMM core: 128x128 tile, BK=32, 4 waves 2x2, dbuf LDS via
// global_load_lds(16B), slot-XOR swizzle (pre-swizzled source).
// ---------------------------------------------------------------------------
#define GEMM_CORE(Aptr, Bptr)                                                  \
    __shared__ __align__(16) char lds[32768];                                  \
    const int t = threadIdx.x, w = t >> 6, l = t & 63;                         \
    const int wr = w >> 1, wc = w & 1;                                         \
    const int rl = l & 15, kh = l >> 4;                                        \
    f32x4 acc[4][4] = {};                                                      \
    {                                                                          \
        const int srow = w * 32 + (l >> 2);                                    \
        const int sslot = (l & 3) ^ ((srow >> 1) & 3);                         \
        const char* Ag0 = (const char*)(Aptr) + (size_t)(m0 + srow) * 1024 + sslot * 16;      \
        const char* Ag1 = (const char*)(Aptr) + (size_t)(m0 + srow + 16) * 1024 + (((l & 3) ^ (((srow + 16) >> 1) & 3)) * 16); \
        const char* Bg0 = (const char*)(Bptr) + (size_t)(n0 + srow) * 1024 + sslot * 16;      \
        const char* Bg1 = (const char*)(Bptr) + (size_t)(n0 + srow + 16) * 1024 + (((l & 3) ^ (((srow + 16) >> 1) & 3)) * 16); \
        for (int kt = 0; kt < 16; ++kt) {                                      \
            if (kt == 0) {                                                     \
                GLOAD_LDS16(Ag0, lds + w * 2048);                              \
                GLOAD_LDS16(Ag1, lds + w * 2048 + 1024);                       \
                GLOAD_LDS16(Bg0, lds + 8192 + w * 2048);                       \
                GLOAD_LDS16(Bg1, lds + 8192 + w * 2048 + 1024);                \
                __syncthreads();                                               \
            }                                                                  \
            const int buf = kt & 1;                                            \
            if (kt < 15) {                                                     \
                const int kb = (kt + 1) * 64;                                  \
                char* Al = lds + (buf ^ 1) * 16384;                            \
                char* Bl = Al + 8192;                                          \
                GLOAD_LDS16(Ag0 + kb, Al + w * 2048);                          \
                GLOAD_LDS16(Ag1 + kb, Al + w * 2048 + 1024);                   \
                GLOAD_LDS16(Bg0 + kb, Bl + w * 2048);                          \
                GLOAD_LDS16(Bg1 + kb, Bl + w * 2048 + 1024);                   \
            }                                                                  \
            const char* Al = lds + buf * 16384;                                \
            const char* Bl = Al + 8192;                                        \
            bf16x8 af[4], bfr[4];                                              \
            _Pragma("unroll")                                                  \
            for (int i = 0; i < 4; ++i) {                                      \
                int row = wr * 64 + i * 16 + rl;                               \
                af[i] = *(const bf16x8*)(Al + row * 64 + ((kh ^ ((row >> 1) & 3)) << 4)); \
                int col = wc * 64 + i * 16 + rl;                               \
                bfr[i] = *(const bf16x8*)(Bl + col * 64 + ((kh ^ ((col >> 1) & 3)) << 4)); \
            }                                                                  \
            _Pragma("unroll")                                                  \
            for (int i = 0; i < 4; ++i)                                        \
                _Pragma("unroll")                                              \
                for (int j = 0; j < 4; ++j)                                    \
                    acc[i][j] = MFMA16(af[i], bfr[j], acc[i][j]);              \
            __syncthreads();                                                   \
        }                                                                      \
    }

// QKV: A = xT, B = Wt[z].  Q/K bf16 [B][H][S][DH]; V bf16 TRANSPOSED
// [B][H][DH][S] so attention can stage V^T rows directly.
__global__ __launch_bounds__(256) void qkv_mm(
    const unsigned short* __restrict__ xT, const unsigned short* __restrict__ Wt,
    const float* __restrict__ bq, const float* __restrict__ bk,
    const float* __restrict__ bv,
    unsigned short* __restrict__ Qb, unsigned short* __restrict__ Kb,
    unsigned short* __restrict__ Vb)
{
    const int z = blockIdx.z;
    const unsigned short* Bt = Wt + (size_t)z * EMB * CC;
    const float* bias = (z == 0) ? bq : (z == 1) ? bk : bv;
    const int m0 = blockIdx.x * 128, n0 = blockIdx.y * 128;

    GEMM_CORE(xT, Bt)

    if (z == 2) {
        // V^T: [B][H][DH][S], 4 consecutive s -> vector store
        #pragma unroll
        for (int i = 0; i < 4; ++i) {
            #pragma unroll
            for (int j = 0; j < 4; ++j) {
                int n = n0 + wc * 64 + j * 16 + rl;
                int h = n >> 6, d = n & 63;
                float bi = bias[n];
                int mb = m0 + wr * 64 + i * 16 + kh * 4;
                int b = mb >> 10, s = mb & 1023;
                bf16x4 o;
                #pragma unroll
                for (int r = 0; r < 4; ++r) o[r] = (__bf16)(acc[i][j][r] + bi);
                *(bf16x4*)((__bf16*)Vb + (((size_t)(b * HEADS + h)) * DH + d) * SS + s) = o;
            }
        }
    } else {
        unsigned short* outp = (z == 0) ? Qb : Kb;
        #pragma unroll
        for (int i = 0; i < 4; ++i) {
            #pragma unroll
            for (int j = 0; j < 4; ++j) {
                int n = n0 + wc * 64 + j * 16 + rl;
                int h = n >> 6, d = n & 63;
                float bi = bias[n];
                #pragma unroll
                for (int r = 0; r < 4; ++r) {
                    int m = m0 + wr * 64 + i * 16 + kh * 4 + r;
                    int b = m >> 10, s = m & 1023;
                    ((__bf16*)outp)[(((size_t)(b * HEADS + h)) * SS + s) * DH + d] =
                        (__bf16)(acc[i][j][r] + bi);
                }
            }
        }
    }
}

// proj: A = AO bf16, B = Wot; out Y fp32 [B][C][S] = acc + bo + x residual.
__global__ __launch_bounds__(256) void proj_mm(
    const unsigned short* __restrict__ AO, const unsigned short* __restrict__ Wot,
    const float* __restrict__ bo, const float* __restrict__ x,
    float* __restrict__ Y)
{
    const int m0 = blockIdx.x * 128, n0 = blockIdx.y * 128;

    GEMM_CORE(AO, Wot)

    #pragma unroll
    for (int i = 0; i < 4; ++i) {
        #pragma unroll
        for (int j = 0; j < 4; ++j) {
            int n = n0 + wc * 64 + j * 16 + rl;
            float bi = bo[n];
            int mb = m0 + wr * 64 + i * 16 + kh * 4;
            int b = mb >> 10, s = mb & 1023;
            const float4 xr = *(const float4*)(x + ((size_t)b * CC + n) * SS + s);
            float4 o;
            o.x = acc[i][j][0] + bi + xr.x;
            o.y = acc[i][j][1] + bi + xr.y;
            o.z = acc[i][j][2] + bi + xr.z;
            o.w = acc[i][j][3] + bi + xr.w;
            *(float4*)(Y + ((size_t)b * CC + n) * SS + s) = o;
        }
    }
}

// ---------------------------------------------------------------------------
// MFMA flash attention v3.  KVBLK=64, 4 waves x 32 q-rows (2 Q-frag columns
// per wave) -> K/V LDS reads amortized over 2x work.  K and V^T staged via
// global_load_lds (pre-swizzled source), 2-phase prefetch, one barrier/tile,
// defer-max softmax in exp2 domain, setprio around MFMA, XCD-aware remap.
// LDS: 2 x (K 8KB + Vt 8KB) + P 4x4KB = 48KB.
// ---------------------------------------------------------------------------
__global__ __launch_bounds__(256) void attn_mfma(
    const unsigned short* __restrict__ Q, const unsigned short* __restrict__ K,
    const unsigned short* __restrict__ V, unsigned short* __restrict__ Aout)
{
    __shared__ __align__(16) char lds[49152];

    // XCD-aware remap: 8 q-blocks of one (b,h) stay on one XCD.
    const int wg  = blockIdx.x;          // 0..511
    const int xcd = wg & 7;
    const int idx = wg >> 3;             // 0..63
    const int pair = xcd * 8 + (idx >> 3);   // 0..63
    const int qb   = idx & 7;
    const int h = pair & 7;
    const int b = pair >> 3;
    const int q0 = qb * 128;

    const size_t kbase = ((size_t)b * HEADS + h) * SS * DH;   // Q,K layout
    const size_t vbase = ((size_t)b * HEADS + h) * DH * SS;   // V^T layout

    const int t  = threadIdx.x;
    const int w  = t >> 6;
    const int l  = t & 63;
    const int g  = l >> 4;
    const int qi = l & 15;
    char* Pl = lds + 32768 + w * 4096;

    // Q fragments resident in registers: 2 q-columns (u) x 2 k-halves (c)
    bf16x8 qf[2][2];
    #pragma unroll
    for (int u = 0; u < 2; ++u) {
        const unsigned short* qrow =
            Q + kbase + (size_t)(q0 + w * 32 + u * 16 + qi) * DH;
        qf[u][0] = *(const bf16x8*)(qrow + g * 8);
        qf[u][1] = *(const bf16x8*)(qrow + 32 + g * 8);
    }

    // staging addresses (pre-swizzled source, linear LDS dest)
    const int srow = t >> 3;             // 0..31
    const int seg  = t & 7;
    const unsigned short* kg0 = K + kbase + (size_t)srow * DH + ((seg ^ (srow & 7)) * 8);
    const unsigned short* vg0 = V + vbase + (size_t)srow * SS + ((seg ^ (srow & 7)) * 8);

#define ATTN_STAGE(bb, ktn)                                                    \
    GLOAD_LDS16(kg0 + (ktn) * 4096, lds + (bb) + t * 16);                      \
    GLOAD_LDS16(kg0 + (ktn) * 4096 + 2048, lds + (bb) + 4096 + t * 16);        \
    GLOAD_LDS16(vg0 + (ktn) * 64, lds + (bb) + 8192 + t * 16);                 \
    GLOAD_LDS16(vg0 + (ktn) * 64 + 32768, lds + (bb) + 12288 + t * 16);

    f32x4 O[4][2] = {};
    float m2[2]   = {-1e30f, -1e30f};
    float lsum[2] = {0.f, 0.f};
    const float cscale = 0.125f * 1.44269504f;   // DH^-0.5 * log2(e)

    int bufb = 0;
    ATTN_STAGE(0, 0)
    __syncthreads();

    for (int kt = 0; kt < 16; ++kt) {
        if (kt < 15) { ATTN_STAGE(bufb ^ 16384, kt + 1) }

        const char* Kl = lds + bufb;
        const char* Vl = lds + bufb + 8192;

        // ---- QK^T swapped: st[tt][u][r] = S^T[kk=tt*16+g*4+r][q] ----
        f32x4 st[4][2] = {};
        __builtin_amdgcn_s_setprio(1);
        #pragma unroll
        for (int tt = 0; tt < 4; ++tt) {
            int row = tt * 16 + qi;
            bf16x8 kf0 = *(const bf16x8*)(Kl + row * 128 +
                          ((g * 16) ^ ((row & 7) << 4)));
            bf16x8 kf1 = *(const bf16x8*)(Kl + row * 128 +
                          ((64 + g * 16) ^ ((row & 7) << 4)));
            #pragma unroll
            for (int u = 0; u < 2; ++u) {
                st[tt][u] = MFMA16(kf0, qf[u][0], st[tt][u]);
                st[tt][u] = MFMA16(kf1, qf[u][1], st[tt][u]);
            }
        }
        __builtin_amdgcn_s_setprio(0);

        // ---- softmax (exp2 domain, defer-max THR=8), per q-column ----
        float pmax[2] = {-1e30f, -1e30f};
        #pragma unroll
        for (int tt = 0; tt < 4; ++tt)
            #pragma unroll
            for (int u = 0; u < 2; ++u)
                #pragma unroll
                for (int r = 0; r < 4; ++r) {
                    float v = st[tt][u][r] * cscale;
                    st[tt][u][r] = v;
                    pmax[u] = fmaxf(pmax[u], v);
                }
        #pragma unroll
        for (int u = 0; u < 2; ++u) {
            if (!__all(pmax[u] <= m2[u] + 8.0f)) {
                float gm = fmaxf(pmax[u], __shfl_xor(pmax[u], 16));
                gm = fmaxf(gm, __shfl_xor(gm, 32));
                float newm = fmaxf(m2[u], gm);
                float alpha = EXP2F(m2[u] - newm);
                #pragma unroll
                for (int dt = 0; dt < 4; ++dt)
                    #pragma unroll
                    for (int r = 0; r < 4; ++r) O[dt][u][r] *= alpha;
                lsum[u] *= alpha;
                m2[u] = newm;
            }
            #pragma unroll
            for (int tt = 0; tt < 4; ++tt) {
                bf16x4 pk;
                #pragma unroll
                for (int r = 0; r < 4; ++r) {
                    float p = EXP2F(st[tt][u][r] - m2[u]);
                    lsum[u] += p;
                    pk[r] = (__bf16)p;
                }
                *(bf16x4*)(Pl + u * 2048 + qi * 128 +
                           ((tt * 32 + g * 8) ^ ((qi & 7) << 4))) = pk;
            }
        }

        // ---- PV: O^T[d][q] += V^T[d][k] P^T[k][q] ----
        bf16x8 pf[2][2];
        #pragma unroll
        for (int u = 0; u < 2; ++u)
            #pragma unroll
            for (int hh = 0; hh < 2; ++hh)
                pf[u][hh] = *(const bf16x8*)(Pl + u * 2048 + qi * 128 +
                             ((hh * 64 + g * 16) ^ ((qi & 7) << 4)));
        __builtin_amdgcn_s_setprio(1);
        #pragma unroll
        for (int dt = 0; dt < 4; ++dt) {
            int d = dt * 16 + qi;
            bf16x8 vf0 = *(const bf16x8*)(Vl + d * 128 + ((g * 16) ^ ((d & 7) << 4)));
            bf16x8 vf1 = *(const bf16x8*)(Vl + d * 128 + ((64 + g * 16) ^ ((d & 7) << 4)));
            #pragma unroll
            for (int u = 0; u < 2; ++u) {
                O[dt][u] = MFMA16(vf0, pf[u][0], O[dt][u]);
                O[dt][u] = MFMA16(vf1, pf[u][1], O[dt][u]);
            }
        }
        __builtin_amdgcn_s_setprio(0);

        __syncthreads();
        bufb ^= 16384;
    }

    // ---- epilogue ----
    #pragma unroll
    for (int u = 0; u < 2; ++u) {
        float ls = lsum[u];
        ls += __shfl_xor(ls, 16);
        ls += __shfl_xor(ls, 32);
        const float inv = __builtin_amdgcn_rcpf(ls);
        unsigned short* orow = Aout +
            ((size_t)b * SS + q0 + w * 32 + u * 16 + qi) * EMB + h * DH;
        #pragma unroll
        for (int dt = 0; dt < 4; ++dt) {
            bf16x4 o;
            #pragma unroll
            for (int r = 0; r < 4; ++r) o[r] = (__bf16)(O[dt][u][r] * inv);
            *(bf16x4*)((__bf16*)orow + dt * 16 + g * 4) = o;
        }
    }
#undef ATTN_STAGE
}

// ---------------------------------------------------------------------------
// GroupNorm, pure streaming on [B][C][S].
// ---------------------------------------------------------------------------
__global__ __launch_bounds__(256) void gnorm2(
    const float* __restrict__ Y, const float* __restrict__ gw,
    const float* __restrict__ gb, float* __restrict__ out)
{
    __shared__ float red[8];
    __shared__ float stats[2];

    const int grp = blockIdx.x;
    const int b   = blockIdx.y;
    const int t   = threadIdx.x;
    const size_t base = ((size_t)b * CC + grp * CPG) * SS;

    float sum = 0.f, sq = 0.f;
    #pragma unroll
    for (int i = 0; i < 16; ++i) {
        float4 v = *(const float4*)(Y + base + (size_t)(t + i * 256) * 4);
        sum += v.x + v.y + v.z + v.w;
        sq  += v.x * v.x + v.y * v.y + v.z * v.z + v.w * v.w;
    }
    #pragma unroll
    for (int off = 32; off; off >>= 1) {
        sum += __shfl_down(sum, off);
        sq  += __shfl_down(sq, off);
    }
    const int wid = t >> 6;
    if ((t & 63) == 0) { red[wid] = sum; red[4 + wid] = sq; }
    __syncthreads();
    if (t == 0) {
        float s1 = red[0] + red[1] + red[2] + red[3];
        float s2 = red[4] + red[5] + red[6] + red[7];
        float mean = s1 / (float)(CPG * SS);
        float var  = s2 / (float)(CPG * SS) - mean * mean;
        stats[0] = mean;
        stats[1] = rsqrtf(var + EPS);
    }
    __syncthreads();
    const float mean = stats[0], rs = stats[1];

    #pragma unroll
    for (int i = 0; i < 16; ++i) {
        size_t idx = (size_t)(t + i * 256) * 4;
        int ch = grp * CPG + (int)(idx >> 10);
        float wgt = gw[ch], bet = gb[ch];
        float4 v = *(const float4*)(Y + base + idx);
        float4 o;
        o.x = (v.x - mean) * rs * wgt + bet;
        o.y = (v.y - mean) * rs * wgt + bet;
        o.z = (v.z - mean) * rs * wgt + bet;
        o.w = (v.w - mean) * rs * wgt + bet;
        *(float4*)(out + base + idx) = o;
    }
}

// ---------------------------------------------------------------------------
extern "C" void kernel_launch(void* const* d_in, const int* in_sizes, int n_in,
                              void* d_out, int out_size, void* d_ws, size_t ws_size,
                              hipStream_t stream) {
    const float* x   = (const float*)d_in[0];
    const float* Wq  = (const float*)d_in[1];
    const float* bq  = (const float*)d_in[2];
    const float* Wk  = (const float*)d_in[3];
    const float* bk  = (const float*)d_in[4];
    const float* Wv  = (const float*)d_in[5];
    const float* bv  = (const float*)d_in[6];
    const float* Wo  = (const float*)d_in[7];
    const float* bo  = (const float*)d_in[8];
    const float* gnw = (const float*)d_in[9];
    const float* gnb = (const float*)d_in[10];
    float* out = (float*)d_out;
    char* ws  = (char*)d_ws;

    unsigned short* xT  = (unsigned short*)(ws);                       //  8 MB
    unsigned short* Wt  = (unsigned short*)(ws + 8388608);             //  2 MB
    unsigned short* Qb  = (unsigned short*)(ws + 10485760);            //  8 MB
    unsigned short* Kb  = (unsigned short*)(ws + 18874368);            //  8 MB
    unsigned short* Vb  = (unsigned short*)(ws + 27262976);            //  8 MB (V^T)
    unsigned short* AO  = (unsigned short*)(ws + 35651584);            //  8 MB
    float*          Y   = (float*)(ws + 44040192);                     // 16 MB

    prep_x<<<dim3(32, 16, 8), 256, 0, stream>>>(x, xT);
    prep_w<<<dim3(16, 16, 4), 256, 0, stream>>>(Wq, Wk, Wv, Wo, Wt);
    qkv_mm<<<dim3(64, 4, 3), 256, 0, stream>>>(xT, Wt, bq, bk, bv, Qb, Kb, Vb);
    attn_mfma<<<dim3(512), 256, 0, stream>>>(Qb, Kb, Vb, AO);
    proj_mm<<<dim3(64, 4), 256, 0, stream>>>(AO, Wt + (size_t)3 * EMB * CC, bo, x, Y);
    gnorm2<<<dim3(32, 8), 256, 0, stream>>>(Y, gnw, gnb, out);
}

// Round 6
// 83.184 us; speedup vs baseline: 14.2457x; 1.0471x over previous
//
#include <hip/hip_runtime.h>

#define BB 8
#define CC 512
#define SS 1024   // H*W
#define EMB 512
#define HEADS 8
#define DH 64
#define GROUPS 32
#define CPG 16
#define EPS 1e-5f

typedef __bf16 bf16x8 __attribute__((ext_vector_type(8)));
typedef __bf16 bf16x4 __attribute__((ext_vector_type(4)));
typedef float f32x4 __attribute__((ext_vector_type(4)));
typedef unsigned short u16x4 __attribute__((ext_vector_type(4)));

__device__ inline unsigned short f2bf(float f) {
    union { float f; unsigned u; } c; c.f = f;
    unsigned u = c.u + 0x7FFF + ((c.u >> 16) & 1);   // RNE
    return (unsigned short)(u >> 16);
}

#if defined(__has_builtin)
#if __has_builtin(__builtin_amdgcn_exp2f)
#define EXP2F(x) __builtin_amdgcn_exp2f(x)
#endif
#endif
#ifndef EXP2F
#define EXP2F(x) __expf(0.69314718f * (x))
#endif

#define MFMA16(a, b, c) __builtin_amdgcn_mfma_f32_16x16x32_bf16((a), (b), (c), 0, 0, 0)
#define GLOAD_LDS16(g, s)                                                     \
    __builtin_amdgcn_global_load_lds(                                         \
        (const __attribute__((address_space(1))) void*)(g),                   \
        (__attribute__((address_space(3))) void*)(s), 16, 0, 0)

// ---------------------------------------------------------------------------
// Prep (fused): blocks 0..4095 transpose x -> xT bf16; 4096..5119 transpose
// the four weight matrices -> Wt bf16 (K-major).
// ---------------------------------------------------------------------------
__global__ __launch_bounds__(256) void prep_all(
    const float* __restrict__ x,
    const float* __restrict__ Wq, const float* __restrict__ Wk,
    const float* __restrict__ Wv, const float* __restrict__ Wo,
    unsigned short* __restrict__ xT, unsigned short* __restrict__ Wt)
{
    __shared__ float tile[32][33];
    const int t = threadIdx.x;

    if (blockIdx.x < 4096) {
        const int i  = blockIdx.x;
        const int s0 = (i & 31) * 32;
        const int c0 = ((i >> 5) & 15) * 32;
        const int b  = i >> 9;
        {
            int c = t >> 3, s4 = (t & 7) * 4;
            float4 v = *(const float4*)(x + ((size_t)b * CC + c0 + c) * SS + s0 + s4);
            tile[c][s4] = v.x; tile[c][s4 + 1] = v.y;
            tile[c][s4 + 2] = v.z; tile[c][s4 + 3] = v.w;
        }
        __syncthreads();
        {
            int sr = t >> 3, c4 = (t & 7) * 4;
            u16x4 o;
            #pragma unroll
            for (int i2 = 0; i2 < 4; ++i2) o[i2] = f2bf(tile[c4 + i2][sr]);
            *(u16x4*)(xT + ((size_t)(b << 10) + s0 + sr) * CC + c0 + c4) = o;
        }
    } else {
        const int i  = blockIdx.x - 4096;
        const int k0 = (i & 15) * 32;
        const int n0 = ((i >> 4) & 15) * 32;
        const int z  = i >> 8;
        const float* W = (z == 0) ? Wq : (z == 1) ? Wk : (z == 2) ? Wv : Wo;
        unsigned short* dst = Wt + (size_t)z * EMB * CC;
        {
            int k = t >> 3, n4 = (t & 7) * 4;
            float4 v = *(const float4*)(W + (size_t)(k0 + k) * EMB + n0 + n4);
            tile[k][n4] = v.x; tile[k][n4 + 1] = v.y;
            tile[k][n4 + 2] = v.z; tile[k][n4 + 3] = v.w;
        }
        __syncthreads();
        {
            int n = t >> 3, k4 = (t & 7) * 4;
            u16x4 o;
            #pragma unroll
            for (int i2 = 0; i2 < 4; ++i2) o[i2] = f2bf(tile[k4 + i2][n]);
            *(u16x4*)(dst + (size_t)(n0 + n) * CC + k0 + k4) = o;
        }
    }
}

// ---------------------------------------------------------------------------
// MFMA GEMM core: 128x128 tile, BK=32, 4 waves 2x2, dbuf LDS via
// global_load_lds(16B), slot-XOR swizzle (pre-swizzled source).
// ---------------------------------------------------------------------------
#define GEMM_CORE(Aptr, Bptr)                                                  \
    __shared__ __align__(16) char lds[32768];                                  \
    const int t = threadIdx.x, w = t >> 6, l = t & 63;                         \
    const int wr = w >> 1, wc = w & 1;                                         \
    const int rl = l & 15, kh = l >> 4;                                        \
    f32x4 acc[4][4] = {};                                                      \
    {                                                                          \
        const int srow = w * 32 + (l >> 2);                                    \
        const int sslot = (l & 3) ^ ((srow >> 1) & 3);                         \
        const char* Ag0 = (const char*)(Aptr) + (size_t)(m0 + srow) * 1024 + sslot * 16;      \
        const char* Ag1 = (const char*)(Aptr) + (size_t)(m0 + srow + 16) * 1024 + (((l & 3) ^ (((srow + 16) >> 1) & 3)) * 16); \
        const char* Bg0 = (const char*)(Bptr) + (size_t)(n0 + srow) * 1024 + sslot * 16;      \
        const char* Bg1 = (const char*)(Bptr) + (size_t)(n0 + srow + 16) * 1024 + (((l & 3) ^ (((srow + 16) >> 1) & 3)) * 16); \
        for (int kt = 0; kt < 16; ++kt) {                                      \
            if (kt == 0) {                                                     \
                GLOAD_LDS16(Ag0, lds + w * 2048);                              \
                GLOAD_LDS16(Ag1, lds + w * 2048 + 1024);                       \
                GLOAD_LDS16(Bg0, lds + 8192 + w * 2048);                       \
                GLOAD_LDS16(Bg1, lds + 8192 + w * 2048 + 1024);                \
                __syncthreads();                                               \
            }                                                                  \
            const int buf = kt & 1;                                            \
            if (kt < 15) {                                                     \
                const int kb = (kt + 1) * 64;                                  \
                char* Al = lds + (buf ^ 1) * 16384;                            \
                char* Bl = Al + 8192;                                          \
                GLOAD_LDS16(Ag0 + kb, Al + w * 2048);                          \
                GLOAD_LDS16(Ag1 + kb, Al + w * 2048 + 1024);                   \
                GLOAD_LDS16(Bg0 + kb, Bl + w * 2048);                          \
                GLOAD_LDS16(Bg1 + kb, Bl + w * 2048 + 1024);                   \
            }                                                                  \
            const char* Al = lds + buf * 16384;                                \
            const char* Bl = Al + 8192;                                        \
            bf16x8 af[4], bfr[4];                                              \
            _Pragma("unroll")                                                  \
            for (int i = 0; i < 4; ++i) {                                      \
                int row = wr * 64 + i * 16 + rl;                               \
                af[i] = *(const bf16x8*)(Al + row * 64 + ((kh ^ ((row >> 1) & 3)) << 4)); \
                int col = wc * 64 + i * 16 + rl;                               \
                bfr[i] = *(const bf16x8*)(Bl + col * 64 + ((kh ^ ((col >> 1) & 3)) << 4)); \
            }                                                                  \
            _Pragma("unroll")                                                  \
            for (int i = 0; i < 4; ++i)                                        \
                _Pragma("unroll")                                              \
                for (int j = 0; j < 4; ++j)                                    \
                    acc[i][j] = MFMA16(af[i], bfr[j], acc[i][j]);              \
            __syncthreads();                                                   \
        }                                                                      \
    }

// QKV: A = xT, B = Wt[z].  Q scaled by DH^-0.5*log2(e) (softmax scale
// folded in).  Q/K bf16 [B][H][S][DH]; V bf16 transposed [B][H][DH][S].
__global__ __launch_bounds__(256) void qkv_mm(
    const unsigned short* __restrict__ xT, const unsigned short* __restrict__ Wt,
    const float* __restrict__ bq, const float* __restrict__ bk,
    const float* __restrict__ bv,
    unsigned short* __restrict__ Qb, unsigned short* __restrict__ Kb,
    unsigned short* __restrict__ Vb)
{
    const int z = blockIdx.z;
    const unsigned short* Bt = Wt + (size_t)z * EMB * CC;
    const float* bias = (z == 0) ? bq : (z == 1) ? bk : bv;
    const int m0 = blockIdx.x * 128, n0 = blockIdx.y * 128;

    GEMM_CORE(xT, Bt)

    if (z == 2) {
        // V^T: [B][H][DH][S], 4 consecutive s -> vector store
        #pragma unroll
        for (int i = 0; i < 4; ++i) {
            #pragma unroll
            for (int j = 0; j < 4; ++j) {
                int n = n0 + wc * 64 + j * 16 + rl;
                int h = n >> 6, d = n & 63;
                float bi = bias[n];
                int mb = m0 + wr * 64 + i * 16 + kh * 4;
                int b = mb >> 10, s = mb & 1023;
                bf16x4 o;
                #pragma unroll
                for (int r = 0; r < 4; ++r) o[r] = (__bf16)(acc[i][j][r] + bi);
                *(bf16x4*)((__bf16*)Vb + (((size_t)(b * HEADS + h)) * DH + d) * SS + s) = o;
            }
        }
    } else {
        unsigned short* outp = (z == 0) ? Qb : Kb;
        const float qs = (z == 0) ? 0.1803368801f : 1.0f;   // 0.125*log2(e)
        #pragma unroll
        for (int i = 0; i < 4; ++i) {
            #pragma unroll
            for (int j = 0; j < 4; ++j) {
                int n = n0 + wc * 64 + j * 16 + rl;
                int h = n >> 6, d = n & 63;
                float bi = bias[n];
                #pragma unroll
                for (int r = 0; r < 4; ++r) {
                    int m = m0 + wr * 64 + i * 16 + kh * 4 + r;
                    int b = m >> 10, s = m & 1023;
                    ((__bf16*)outp)[(((size_t)(b * HEADS + h)) * SS + s) * DH + d] =
                        (__bf16)((acc[i][j][r] + bi) * qs);
                }
            }
        }
    }
}

// proj: A = AO bf16, B = Wot; out Y **bf16** [B][C][S] = acc + bo + residual.
__global__ __launch_bounds__(256) void proj_mm(
    const unsigned short* __restrict__ AO, const unsigned short* __restrict__ Wot,
    const float* __restrict__ bo, const float* __restrict__ x,
    unsigned short* __restrict__ Yb)
{
    const int m0 = blockIdx.x * 128, n0 = blockIdx.y * 128;

    GEMM_CORE(AO, Wot)

    #pragma unroll
    for (int i = 0; i < 4; ++i) {
        #pragma unroll
        for (int j = 0; j < 4; ++j) {
            int n = n0 + wc * 64 + j * 16 + rl;
            float bi = bo[n];
            int mb = m0 + wr * 64 + i * 16 + kh * 4;
            int b = mb >> 10, s = mb & 1023;
            const float4 xr = *(const float4*)(x + ((size_t)b * CC + n) * SS + s);
            bf16x4 o;
            o[0] = (__bf16)(acc[i][j][0] + bi + xr.x);
            o[1] = (__bf16)(acc[i][j][1] + bi + xr.y);
            o[2] = (__bf16)(acc[i][j][2] + bi + xr.z);
            o[3] = (__bf16)(acc[i][j][3] + bi + xr.w);
            *(bf16x4*)((__bf16*)Yb + ((size_t)b * CC + n) * SS + s) = o;
        }
    }
}

// ---------------------------------------------------------------------------
// MFMA flash attention v3.1.  KVBLK=64, 4 waves x 32 q-rows, K and V^T staged
// via global_load_lds (pre-swizzled source), 2-phase prefetch, one barrier
// per tile, defer-max softmax (scale pre-folded into Q), setprio, XCD remap.
// LDS: 2 x (K 8KB + Vt 8KB) + P 4x4KB = 48KB.
// ---------------------------------------------------------------------------
__global__ __launch_bounds__(256) void attn_mfma(
    const unsigned short* __restrict__ Q, const unsigned short* __restrict__ K,
    const unsigned short* __restrict__ V, unsigned short* __restrict__ Aout)
{
    __shared__ __align__(16) char lds[49152];

    // XCD-aware remap: 8 q-blocks of one (b,h) stay on one XCD.
    const int wg  = blockIdx.x;          // 0..511
    const int xcd = wg & 7;
    const int idx = wg >> 3;             // 0..63
    const int pair = xcd * 8 + (idx >> 3);   // 0..63
    const int qb   = idx & 7;
    const int h = pair & 7;
    const int b = pair >> 3;
    const int q0 = qb * 128;

    const size_t kbase = ((size_t)b * HEADS + h) * SS * DH;   // Q,K layout
    const size_t vbase = ((size_t)b * HEADS + h) * DH * SS;   // V^T layout

    const int t  = threadIdx.x;
    const int w  = t >> 6;
    const int l  = t & 63;
    const int g  = l >> 4;
    const int qi = l & 15;
    char* Pl = lds + 32768 + w * 4096;

    // Q fragments resident in registers: 2 q-columns (u) x 2 k-halves
    bf16x8 qf[2][2];
    #pragma unroll
    for (int u = 0; u < 2; ++u) {
        const unsigned short* qrow =
            Q + kbase + (size_t)(q0 + w * 32 + u * 16 + qi) * DH;
        qf[u][0] = *(const bf16x8*)(qrow + g * 8);
        qf[u][1] = *(const bf16x8*)(qrow + 32 + g * 8);
    }

    // staging addresses (pre-swizzled source, linear LDS dest)
    const int srow = t >> 3;             // 0..31
    const int seg  = t & 7;
    const unsigned short* kg0 = K + kbase + (size_t)srow * DH + ((seg ^ (srow & 7)) * 8);
    const unsigned short* vg0 = V + vbase + (size_t)srow * SS + ((seg ^ (srow & 7)) * 8);

#define ATTN_STAGE(bb, ktn)                                                    \
    GLOAD_LDS16(kg0 + (ktn) * 4096, lds + (bb) + t * 16);                      \
    GLOAD_LDS16(kg0 + (ktn) * 4096 + 2048, lds + (bb) + 4096 + t * 16);        \
    GLOAD_LDS16(vg0 + (ktn) * 64, lds + (bb) + 8192 + t * 16);                 \
    GLOAD_LDS16(vg0 + (ktn) * 64 + 32768, lds + (bb) + 12288 + t * 16);

    f32x4 O[4][2] = {};
    float m2[2]   = {-1e30f, -1e30f};
    float lsum[2] = {0.f, 0.f};

    int bufb = 0;
    ATTN_STAGE(0, 0)
    __syncthreads();

    for (int kt = 0; kt < 16; ++kt) {
        if (kt < 15) { ATTN_STAGE(bufb ^ 16384, kt + 1) }

        const char* Kl = lds + bufb;
        const char* Vl = lds + bufb + 8192;

        // ---- QK^T swapped (scores already in log2 domain via Q scale) ----
        f32x4 st[4][2] = {};
        __builtin_amdgcn_s_setprio(1);
        #pragma unroll
        for (int tt = 0; tt < 4; ++tt) {
            int row = tt * 16 + qi;
            bf16x8 kf0 = *(const bf16x8*)(Kl + row * 128 +
                          ((g * 16) ^ ((row & 7) << 4)));
            bf16x8 kf1 = *(const bf16x8*)(Kl + row * 128 +
                          ((64 + g * 16) ^ ((row & 7) << 4)));
            #pragma unroll
            for (int u = 0; u < 2; ++u) {
                st[tt][u] = MFMA16(kf0, qf[u][0], st[tt][u]);
                st[tt][u] = MFMA16(kf1, qf[u][1], st[tt][u]);
            }
        }
        __builtin_amdgcn_s_setprio(0);

        // ---- softmax (exp2 domain, defer-max THR=8), per q-column ----
        float pmax[2] = {-1e30f, -1e30f};
        #pragma unroll
        for (int tt = 0; tt < 4; ++tt)
            #pragma unroll
            for (int u = 0; u < 2; ++u)
                #pragma unroll
                for (int r = 0; r < 4; ++r)
                    pmax[u] = fmaxf(pmax[u], st[tt][u][r]);
        #pragma unroll
        for (int u = 0; u < 2; ++u) {
            if (!__all(pmax[u] <= m2[u] + 8.0f)) {
                float gm = fmaxf(pmax[u], __shfl_xor(pmax[u], 16));
                gm = fmaxf(gm, __shfl_xor(gm, 32));
                float newm = fmaxf(m2[u], gm);
                float alpha = EXP2F(m2[u] - newm);
                #pragma unroll
                for (int dt = 0; dt < 4; ++dt)
                    #pragma unroll
                    for (int r = 0; r < 4; ++r) O[dt][u][r] *= alpha;
                lsum[u] *= alpha;
                m2[u] = newm;
            }
            #pragma unroll
            for (int tt = 0; tt < 4; ++tt) {
                bf16x4 pk;
                #pragma unroll
                for (int r = 0; r < 4; ++r) {
                    float p = EXP2F(st[tt][u][r] - m2[u]);
                    lsum[u] += p;
                    pk[r] = (__bf16)p;
                }
                *(bf16x4*)(Pl + u * 2048 + qi * 128 +
                           ((tt * 32 + g * 8) ^ ((qi & 7) << 4))) = pk;
            }
        }

        // ---- PV: O^T[d][q] += V^T[d][k] P^T[k][q] ----
        bf16x8 pf[2][2];
        #pragma unroll
        for (int u = 0; u < 2; ++u)
            #pragma unroll
            for (int hh = 0; hh < 2; ++hh)
                pf[u][hh] = *(const bf16x8*)(Pl + u * 2048 + qi * 128 +
                             ((hh * 64 + g * 16) ^ ((qi & 7) << 4)));
        __builtin_amdgcn_s_setprio(1);
        #pragma unroll
        for (int dt = 0; dt < 4; ++dt) {
            int d = dt * 16 + qi;
            bf16x8 vf0 = *(const bf16x8*)(Vl + d * 128 + ((g * 16) ^ ((d & 7) << 4)));
            bf16x8 vf1 = *(const bf16x8*)(Vl + d * 128 + ((64 + g * 16) ^ ((d & 7) << 4)));
            #pragma unroll
            for (int u = 0; u < 2; ++u) {
                O[dt][u] = MFMA16(vf0, pf[u][0], O[dt][u]);
                O[dt][u] = MFMA16(vf1, pf[u][1], O[dt][u]);
            }
        }
        __builtin_amdgcn_s_setprio(0);

        __syncthreads();
        bufb ^= 16384;
    }

    // ---- epilogue ----
    #pragma unroll
    for (int u = 0; u < 2; ++u) {
        float ls = lsum[u];
        ls += __shfl_xor(ls, 16);
        ls += __shfl_xor(ls, 32);
        const float inv = __builtin_amdgcn_rcpf(ls);
        unsigned short* orow = Aout +
            ((size_t)b * SS + q0 + w * 32 + u * 16 + qi) * EMB + h * DH;
        #pragma unroll
        for (int dt = 0; dt < 4; ++dt) {
            bf16x4 o;
            #pragma unroll
            for (int r = 0; r < 4; ++r) o[r] = (__bf16)(O[dt][u][r] * inv);
            *(bf16x4*)((__bf16*)orow + dt * 16 + g * 4) = o;
        }
    }
#undef ATTN_STAGE
}

// ---------------------------------------------------------------------------
// GroupNorm: Y bf16 [B][C][S] read ONCE into LDS (32KB/group), stats from
// LDS, normalize from LDS, fp32 out.  One block per (group, batch).
// ---------------------------------------------------------------------------
__global__ __launch_bounds__(256) void gnorm3(
    const __bf16* __restrict__ Yb, const float* __restrict__ gw,
    const float* __restrict__ gb, float* __restrict__ out)
{
    __shared__ __align__(16) __bf16 ybuf[CPG * SS];   // 32 KB
    __shared__ float red[8];
    __shared__ float stats[2];

    const int grp = blockIdx.x;
    const int b   = blockIdx.y;
    const int t   = threadIdx.x;
    const size_t base = ((size_t)b * CC + grp * CPG) * SS;   // 16384 elems
    const __bf16* src = Yb + base;

    float sum = 0.f, sq = 0.f;
    #pragma unroll
    for (int i = 0; i < 8; ++i) {
        int off = i * 2048 + t * 8;
        bf16x8 v = *(const bf16x8*)(src + off);
        *(bf16x8*)(ybuf + off) = v;
        #pragma unroll
        for (int j = 0; j < 8; ++j) {
            float f = (float)v[j];
            sum += f; sq += f * f;
        }
    }
    #pragma unroll
    for (int off = 32; off; off >>= 1) {
        sum += __shfl_down(sum, off);
        sq  += __shfl_down(sq, off);
    }
    const int wid = t >> 6;
    if ((t & 63) == 0) { red[wid] = sum; red[4 + wid] = sq; }
    __syncthreads();
    if (t == 0) {
        float s1 = red[0] + red[1] + red[2] + red[3];
        float s2 = red[4] + red[5] + red[6] + red[7];
        float mean = s1 / (float)(CPG * SS);
        float var  = s2 / (float)(CPG * SS) - mean * mean;
        stats[0] = mean;
        stats[1] = rsqrtf(var + EPS);
    }
    __syncthreads();
    const float mean = stats[0], rs = stats[1];

    #pragma unroll
    for (int i = 0; i < 8; ++i) {
        int off = i * 2048 + t * 8;
        int ch = grp * CPG + (off >> 10);
        float wgt = gw[ch] * rs, bet = gb[ch] - mean * rs * gw[ch];
        bf16x8 v = *(const bf16x8*)(ybuf + off);
        float4 o0, o1;
        o0.x = (float)v[0] * wgt + bet; o0.y = (float)v[1] * wgt + bet;
        o0.z = (float)v[2] * wgt + bet; o0.w = (float)v[3] * wgt + bet;
        o1.x = (float)v[4] * wgt + bet; o1.y = (float)v[5] * wgt + bet;
        o1.z = (float)v[6] * wgt + bet; o1.w = (float)v[7] * wgt + bet;
        *(float4*)(out + base + off)     = o0;
        *(float4*)(out + base + off + 4) = o1;
    }
}

// ---------------------------------------------------------------------------
extern "C" void kernel_launch(void* const* d_in, const int* in_sizes, int n_in,
                              void* d_out, int out_size, void* d_ws, size_t ws_size,
                              hipStream_t stream) {
    const float* x   = (const float*)d_in[0];
    const float* Wq  = (const float*)d_in[1];
    const float* bq  = (const float*)d_in[2];
    const float* Wk  = (const float*)d_in[3];
    const float* bk  = (const float*)d_in[4];
    const float* Wv  = (const float*)d_in[5];
    const float* bv  = (const float*)d_in[6];
    const float* Wo  = (const float*)d_in[7];
    const float* bo  = (const float*)d_in[8];
    const float* gnw = (const float*)d_in[9];
    const float* gnb = (const float*)d_in[10];
    float* out = (float*)d_out;
    char* ws  = (char*)d_ws;

    unsigned short* xT  = (unsigned short*)(ws);                       //  8 MB
    unsigned short* Wt  = (unsigned short*)(ws + 8388608);             //  2 MB
    unsigned short* Qb  = (unsigned short*)(ws + 10485760);            //  8 MB
    unsigned short* Kb  = (unsigned short*)(ws + 18874368);            //  8 MB
    unsigned short* Vb  = (unsigned short*)(ws + 27262976);            //  8 MB (V^T)
    unsigned short* AO  = (unsigned short*)(ws + 35651584);            //  8 MB
    unsigned short* Yb  = (unsigned short*)(ws + 44040192);            //  8 MB (bf16)

    prep_all<<<dim3(5120), 256, 0, stream>>>(x, Wq, Wk, Wv, Wo, xT, Wt);
    qkv_mm<<<dim3(64, 4, 3), 256, 0, stream>>>(xT, Wt, bq, bk, bv, Qb, Kb, Vb);
    attn_mfma<<<dim3(512), 256, 0, stream>>>(Qb, Kb, Vb, AO);
    proj_mm<<<dim3(64, 4), 256, 0, stream>>>(AO, Wt + (size_t)3 * EMB * CC, bo, x, Yb);
    gnorm3<<<dim3(32, 8), 256, 0, stream>>>((const __bf16*)Yb, gnw, gnb, out);
}